// Round 4
// baseline (978.605 us; speedup 1.0000x reference)
//
#include <hip/hip_runtime.h>
#include <math.h>

// FusionRestormerBlock — bf16 MFMA, fragment-ordered weights.
// v5: k4 GELU via sigmoid form (erff was ~30% VALUBusy), Xg reg-prefetch,
// float4 out-scatter. k1 fully vectorized (float4 in, bhalf8 out). k2/k3
// setprio(1) around the fused QKV MFMA pass (barrier-free wave phase).

#define TPB 256
#define TPB2 512
#define NWIN 2048
#define SCALEF 0.20412414523193154f  // 24^-0.5

typedef __attribute__((ext_vector_type(8))) short bhalf8;
typedef __attribute__((ext_vector_type(4))) float fvec4;

#define MFMA(a, b, c) __builtin_amdgcn_mfma_f32_16x16x32_bf16(a, b, c, 0, 0, 0)

__device__ __forceinline__ short f2bf(float f) {
    unsigned u = __float_as_uint(f);
    u = u + 0x7fffu + ((u >> 16) & 1u);
    return (short)(u >> 16);
}
__device__ __forceinline__ float bf2f(short s) {
    return __uint_as_float(((unsigned)(unsigned short)s) << 16);
}

// Weight region element counts (bf16 elements), all tile-packed
#define N_QKV 147456     // 8 heads x (6 nt x 6 kt) tiles
#define N_QC  49152      // 8 x (2 x 6)
#define N_KV  98304      // 8 x (4 x 6)
#define N_AP  36864      // 12 x 6
#define N_CP  36864
#define N_W1  147456     // 48 x 6
#define N_W2  147456     // 12 nt x 24 ks
#define W_TOT 663552

// per-wave LDS region (shorts): q[0:2560) k[2560:5120) vt[5120:7424)
// sp overlays [0:4608) after q/k consumed; O overlays [0:1536) after sp consumed
#define PW 7424

// ---------------- K0: weight prep (fp32 -> padded bf16, fragment-tile order) ----------------
__global__ __launch_bounds__(TPB) void k0_wprep(
    const float* __restrict__ qkvw, const float* __restrict__ qkvb,
    const float* __restrict__ qw, const float* __restrict__ kvw,
    const float* __restrict__ apw, const float* __restrict__ cpw,
    const float* __restrict__ w1, const float* __restrict__ w2,
    short* __restrict__ Wqkv, short* __restrict__ Wqc, short* __restrict__ Wkv,
    short* __restrict__ Wap, short* __restrict__ Wcp, short* __restrict__ W1b,
    short* __restrict__ W2b, float* __restrict__ qbp)
{
    const int tid = blockIdx.x * TPB + threadIdx.x;
    const int stride = gridDim.x * TPB;
    for (int i = tid; i < N_QKV; i += stride) {
        int tile = i >> 9, pos = i & 511;
        int lane = pos >> 3, j = pos & 7, l16 = lane & 15, g = lane >> 4;
        int h = tile / 36, t2 = tile % 36, nt = t2 / 6, kt = t2 % 6;
        int col = nt * 16 + l16, sub = col >> 5, d = col & 31;
        int k = kt * 32 + g * 8 + j;
        float v = (d < 24) ? qkvw[(sub * 192 + h * 24 + d) * 192 + k] : 0.f;
        Wqkv[i] = f2bf(v);
    }
    for (int i = tid; i < N_QC; i += stride) {
        int tile = i >> 9, pos = i & 511;
        int lane = pos >> 3, j = pos & 7, l16 = lane & 15, g = lane >> 4;
        int h = tile / 12, t2 = tile % 12, nt = t2 / 6, kt = t2 % 6;
        int col = nt * 16 + l16;
        int k = kt * 32 + g * 8 + j;
        float v = (col < 24) ? qw[(h * 24 + col) * 192 + k] : 0.f;
        Wqc[i] = f2bf(v);
    }
    for (int i = tid; i < N_KV; i += stride) {
        int tile = i >> 9, pos = i & 511;
        int lane = pos >> 3, j = pos & 7, l16 = lane & 15, g = lane >> 4;
        int h = tile / 24, t2 = tile % 24, nt = t2 / 6, kt = t2 % 6;
        int col = nt * 16 + l16, sub = col >> 5, d = col & 31;
        int k = kt * 32 + g * 8 + j;
        float v = (d < 24) ? kvw[(sub * 192 + h * 24 + d) * 192 + k] : 0.f;
        Wkv[i] = f2bf(v);
    }
    for (int i = tid; i < N_AP; i += stride) {
        int tile = i >> 9, pos = i & 511;
        int lane = pos >> 3, j = pos & 7, l16 = lane & 15, g = lane >> 4;
        int nt = tile / 6, kt = tile % 6;
        int n = nt * 16 + l16, k = kt * 32 + g * 8 + j;
        Wap[i] = f2bf(apw[n * 192 + k]);
    }
    for (int i = tid; i < N_CP; i += stride) {
        int tile = i >> 9, pos = i & 511;
        int lane = pos >> 3, j = pos & 7, l16 = lane & 15, g = lane >> 4;
        int nt = tile / 6, kt = tile % 6;
        int n = nt * 16 + l16, k = kt * 32 + g * 8 + j;
        Wcp[i] = f2bf(cpw[n * 192 + k]);
    }
    for (int i = tid; i < N_W1; i += stride) {
        int tile = i >> 9, pos = i & 511;
        int lane = pos >> 3, j = pos & 7, l16 = lane & 15, g = lane >> 4;
        int nt = tile / 6, kt = tile % 6;
        int n = nt * 16 + l16, k = kt * 32 + g * 8 + j;
        W1b[i] = f2bf(w1[n * 192 + k]);
    }
    for (int i = tid; i < N_W2; i += stride) {
        int tile = i >> 9, pos = i & 511;
        int lane = pos >> 3, j = pos & 7, l16 = lane & 15, g = lane >> 4;
        int nt = tile / 24, ks = tile % 24;
        int n = nt * 16 + l16, k = ks * 32 + g * 8 + j;
        W2b[i] = f2bf(w2[n * 768 + k]);
    }
    for (int i = tid; i < 768; i += stride) {
        int h = i / 96, col = i % 96, sub = col >> 5, d = col & 31;
        qbp[i] = (d < 24) ? qkvb[sub * 192 + h * 24 + d] : 0.f;
    }
}

// ---------------- K1: tokenize + cln1 (vectorized IO) ----------------
__global__ __launch_bounds__(TPB) void k1_prep(
    const float* __restrict__ xrgb, const float* __restrict__ xsar,
    const float* __restrict__ gamma, const float* __restrict__ beta,
    const float* __restrict__ ln1w, const float* __restrict__ ln1b,
    short* __restrict__ Ag, short* __restrict__ Xg, short* __restrict__ Sg)
{
    __shared__ float s_x[64 * 193];
    __shared__ float s_mu[64], s_rs[64];
    __shared__ float s_cw[768];   // ln1w | ln1b | gamma_b | beta_b
    const int tid = threadIdx.x;
    const int wid = blockIdx.x;
    const int b = wid >> 8, hb = (wid >> 4) & 15, wb = wid & 15;
    const int xbase = ((b * 192) << 14) + ((hb * 8) << 7) + wb * 8;
    const int tok0 = wid * 12288;

    for (int i = tid; i < 192; i += TPB) {
        s_cw[i]       = ln1w[i];
        s_cw[192 + i] = ln1b[i];
        s_cw[384 + i] = gamma[b * 192 + i];
        s_cw[576 + i] = beta[b * 192 + i];
    }
    // ---- float4 loads: 192 c x 8 hrow x 2 half ----
    for (int i = tid; i < 3072; i += TPB) {
        int c = i >> 4, rem = i & 15, hrow = rem >> 1, half = rem & 1;
        float4 v = *(const float4*)&xrgb[xbase + (c << 14) + (hrow << 7) + half * 4];
        int l = hrow * 8 + half * 4;
        s_x[(l + 0) * 193 + c] = v.x;
        s_x[(l + 1) * 193 + c] = v.y;
        s_x[(l + 2) * 193 + c] = v.z;
        s_x[(l + 3) * 193 + c] = v.w;
    }
    __syncthreads();
    {
        int t = tid >> 2, q4 = tid & 3;
        float sum = 0.f, sq = 0.f;
        for (int j = 0; j < 48; j++) {
            float v = s_x[t * 193 + q4 * 48 + j];
            sum += v; sq += v * v;
        }
        sum += __shfl_xor(sum, 1); sum += __shfl_xor(sum, 2);
        sq  += __shfl_xor(sq, 1);  sq  += __shfl_xor(sq, 2);
        float mu = sum * (1.f / 192.f);
        float var = sq * (1.f / 192.f) - mu * mu;
        if (q4 == 0) { s_mu[t] = mu; s_rs[t] = rsqrtf(var + 1e-6f); }
    }
    __syncthreads();
    // ---- packed bhalf8 stores: 1536 chunks of 8 channels ----
    for (int i = tid; i < 1536; i += TPB) {
        int flat = i << 3, t = flat / 192, c0 = flat - t * 192;
        float mu = s_mu[t], rs = s_rs[t];
        bhalf8 xv, av;
#pragma unroll
        for (int j = 0; j < 8; j++) {
            float x = s_x[t * 193 + c0 + j];
            xv[j] = f2bf(x);
            float xn = (x - mu) * rs;
            av[j] = f2bf((xn * s_cw[c0 + j] + s_cw[192 + c0 + j]) * s_cw[384 + c0 + j] + s_cw[576 + c0 + j]);
        }
        *(bhalf8*)&Xg[tok0 + flat] = xv;
        *(bhalf8*)&Ag[tok0 + flat] = av;
    }
    __syncthreads();
    for (int i = tid; i < 3072; i += TPB) {
        int c = i >> 4, rem = i & 15, hrow = rem >> 1, half = rem & 1;
        float4 v = *(const float4*)&xsar[xbase + (c << 14) + (hrow << 7) + half * 4];
        int l = hrow * 8 + half * 4;
        s_x[(l + 0) * 193 + c] = v.x;
        s_x[(l + 1) * 193 + c] = v.y;
        s_x[(l + 2) * 193 + c] = v.z;
        s_x[(l + 3) * 193 + c] = v.w;
    }
    __syncthreads();
    for (int i = tid; i < 1536; i += TPB) {
        int flat = i << 3, t = flat / 192, c0 = flat - t * 192;
        bhalf8 sv;
#pragma unroll
        for (int j = 0; j < 8; j++) sv[j] = f2bf(s_x[t * 193 + c0 + j]);
        *(bhalf8*)&Sg[tok0 + flat] = sv;
    }
}

// ---------------- K2: fused self-attention (8 waves, 1 head/wave, LDS A-tile) ----------------
__global__ __launch_bounds__(TPB2, 2) void k2_self(
    short* __restrict__ Ag, short* __restrict__ Xg,
    const short* __restrict__ Wqkv, const float* __restrict__ qbp,
    const short* __restrict__ Wap, const float* __restrict__ apb,
    const float* __restrict__ relb,
    const float* __restrict__ ln1w, const float* __restrict__ ln1b,
    const float* __restrict__ gamma, const float* __restrict__ beta)
{
    __shared__ short s_a[12800];       // A tile 64x200 (then Xg stage, then Xg-out)
    __shared__ short s_w8[8 * PW];     // per-wave q/k/vt (sp,O overlay); then Ag-out [0:12800)
    __shared__ short s_rb[1800];
    __shared__ float s_part[512];      // [ng:4][row:64][2]
    __shared__ float s_mv[128];        // [row][mu,rs]

    const int tid = threadIdx.x;
    const int wid = blockIdx.x;
    const int b = wid >> 8;
    const int w = tid >> 6;            // wave 0..7 = head
    const int lane = tid & 63;
    const int g = lane >> 4;
    const int l16 = lane & 15;
    const int fo = lane << 3;
    const int tok0 = wid * 12288;
    short* const sq  = &s_w8[w * PW];
    short* const sk  = sq + 2560;
    short* const svt = sq + 5120;
    short* const sp  = sq;             // overlays q/k
    short* const so  = sq;             // O stash overlays sp after PV
    const fvec4 z4 = {0.f, 0.f, 0.f, 0.f};

    // ---- stage A tile (vectorized) + rel bias ----
#pragma unroll
    for (int t = 0; t < 3; t++) {
        int i = tid + t * TPB2;
        int flat = i << 3, row = flat / 192, col = flat - row * 192;
        *(bhalf8*)&s_a[row * 200 + col] = *(const bhalf8*)&Ag[tok0 + flat];
    }
    for (int i = tid; i < 1800; i += TPB2) s_rb[i] = f2bf(relb[i]);
    __syncthreads();

    {
        const int h = w;
        // ---- fused QKV GEMM (one pass, A from LDS) ----
        fvec4 acc[4][6];
#pragma unroll
        for (int mt = 0; mt < 4; mt++)
#pragma unroll
            for (int nt = 0; nt < 6; nt++) acc[mt][nt] = z4;
        __builtin_amdgcn_s_setprio(1);
#pragma unroll
        for (int kt = 0; kt < 6; kt++) {
            bhalf8 af[4];
#pragma unroll
            for (int mt = 0; mt < 4; mt++)
                af[mt] = *(const bhalf8*)&s_a[(mt * 16 + l16) * 200 + kt * 32 + g * 8];
#pragma unroll
            for (int nt = 0; nt < 6; nt++) {
                bhalf8 wf = *(const bhalf8*)&Wqkv[((h * 36 + nt * 6 + kt) << 9) + fo];
#pragma unroll
                for (int mt = 0; mt < 4; mt++)
                    acc[mt][nt] = MFMA(af[mt], wf, acc[mt][nt]);
            }
        }
        __builtin_amdgcn_s_setprio(0);
        // write Q (nt 0,1), K (nt 2,3), V^T (nt 4,5); pads d 24..31 are exact zeros
#pragma unroll
        for (int nt = 0; nt < 6; nt++) {
            float bq = qbp[h * 96 + nt * 16 + l16];
            int d = (nt & 1) * 16 + l16;
#pragma unroll
            for (int mt = 0; mt < 4; mt++)
#pragma unroll
                for (int r = 0; r < 4; r++) {
                    int tok = mt * 16 + g * 4 + r;
                    short bv = f2bf(acc[mt][nt][r] + bq);
                    if (nt < 2)      sq[tok * 40 + d] = bv;
                    else if (nt < 4) sk[tok * 40 + d] = bv;
                    else             svt[d * 72 + tok] = bv;
                }
        }
        // ---- S = Q K^T (wave-local) ----
        fvec4 sacc[4][4];
        {
            bhalf8 qf[4], kf[4];
#pragma unroll
            for (int mt = 0; mt < 4; mt++)
                qf[mt] = *(const bhalf8*)&sq[(mt * 16 + l16) * 40 + g * 8];
#pragma unroll
            for (int nt = 0; nt < 4; nt++)
                kf[nt] = *(const bhalf8*)&sk[(nt * 16 + l16) * 40 + g * 8];
#pragma unroll
            for (int mt = 0; mt < 4; mt++)
#pragma unroll
                for (int nt = 0; nt < 4; nt++)
                    sacc[mt][nt] = MFMA(qf[mt], kf[nt], z4);
        }
        // ---- softmax, P -> sp ----
#pragma unroll
        for (int mt = 0; mt < 4; mt++) {
            float sv[4][4];
#pragma unroll
            for (int nt = 0; nt < 4; nt++) {
                int n = nt * 16 + l16, ki = n >> 3, kj = n & 7;
#pragma unroll
                for (int r = 0; r < 4; r++) {
                    int qq = mt * 16 + g * 4 + r, qi = qq >> 3, qj = qq & 7;
                    int ridx = (qi - ki + 7) * 15 + (qj - kj + 7);
                    sv[nt][r] = sacc[mt][nt][r] * SCALEF + bf2f(s_rb[ridx * 8 + h]);
                }
            }
#pragma unroll
            for (int r = 0; r < 4; r++) {
                float m = fmaxf(fmaxf(sv[0][r], sv[1][r]), fmaxf(sv[2][r], sv[3][r]));
                m = fmaxf(m, __shfl_xor(m, 1)); m = fmaxf(m, __shfl_xor(m, 2));
                m = fmaxf(m, __shfl_xor(m, 4)); m = fmaxf(m, __shfl_xor(m, 8));
                float s = 0.f;
#pragma unroll
                for (int nt = 0; nt < 4; nt++) { sv[nt][r] = __expf(sv[nt][r] - m); s += sv[nt][r]; }
                s += __shfl_xor(s, 1); s += __shfl_xor(s, 2);
                s += __shfl_xor(s, 4); s += __shfl_xor(s, 8);
                float inv = 1.f / s;
#pragma unroll
                for (int nt = 0; nt < 4; nt++)
                    sp[(mt * 16 + g * 4 + r) * 72 + nt * 16 + l16] = f2bf(sv[nt][r] * inv);
            }
        }
        // ---- O = P V ----
        fvec4 oacc[4][2];
#pragma unroll
        for (int mt = 0; mt < 4; mt++) { oacc[mt][0] = z4; oacc[mt][1] = z4; }
#pragma unroll
        for (int ks = 0; ks < 2; ks++) {
            bhalf8 pf[4];
#pragma unroll
            for (int mt = 0; mt < 4; mt++)
                pf[mt] = *(const bhalf8*)&sp[(mt * 16 + l16) * 72 + ks * 32 + g * 8];
#pragma unroll
            for (int nt = 0; nt < 2; nt++) {
                bhalf8 vf = *(const bhalf8*)&svt[(nt * 16 + l16) * 72 + ks * 32 + g * 8];
#pragma unroll
                for (int mt = 0; mt < 4; mt++)
                    oacc[mt][nt] = MFMA(pf[mt], vf, oacc[mt][nt]);
            }
        }
        // ---- stash O [tok][24] in own region ----
#pragma unroll
        for (int nt = 0; nt < 2; nt++) {
            int d = nt * 16 + l16;
            if (d < 24) {
#pragma unroll
                for (int mt = 0; mt < 4; mt++)
#pragma unroll
                    for (int r = 0; r < 4; r++)
                        so[(mt * 16 + g * 4 + r) * 24 + d] = f2bf(oacc[mt][nt][r]);
            }
        }
    }
    __syncthreads();

    // ---- prefetch Xg residual into registers (hides under proj) ----
    bhalf8 xst[3]; int xr[3], xc[3];
#pragma unroll
    for (int t = 0; t < 3; t++) {
        int i = tid + t * TPB2;
        int flat = i << 3; xr[t] = flat / 192; xc[t] = flat - xr[t] * 192;
        xst[t] = *(const bhalf8*)&Xg[tok0 + flat];
    }

    // ---- proj: wave = (mh = w&1: rows mh*32..+32) x (ng = w>>1: cols ng*48..+48) ----
    const int mh = w & 1, ng = w >> 1;
    fvec4 p[2][3];
#pragma unroll
    for (int m = 0; m < 2; m++)
#pragma unroll
        for (int j = 0; j < 3; j++) p[m][j] = z4;
#pragma unroll
    for (int kt = 0; kt < 6; kt++) {
        int c0 = kt * 32 + g * 8;
        int h0 = c0 / 24, d0 = c0 - h0 * 24;
        bhalf8 of[2];
#pragma unroll
        for (int m = 0; m < 2; m++)
            of[m] = *(const bhalf8*)&s_w8[h0 * PW + ((mh * 2 + m) * 16 + l16) * 24 + d0];
#pragma unroll
        for (int j = 0; j < 3; j++) {
            bhalf8 wf = *(const bhalf8*)&Wap[(((ng * 3 + j) * 6 + kt) << 9) + fo];
#pragma unroll
            for (int m = 0; m < 2; m++)
                p[m][j] = MFMA(of[m], wf, p[m][j]);
        }
    }
    // ---- write Xg stage to s_a (A tile dead) ----
#pragma unroll
    for (int t = 0; t < 3; t++)
        *(bhalf8*)&s_a[xr[t] * 200 + xc[t]] = xst[t];
    __syncthreads();

    // ---- x1 = x_rgb + y + apb ; cross-wave LN ----
    float xv[2][3][4];
#pragma unroll
    for (int j = 0; j < 3; j++) {
        int col = ng * 48 + j * 16 + l16;
        float ap = apb[col];
#pragma unroll
        for (int m = 0; m < 2; m++)
#pragma unroll
            for (int r = 0; r < 4; r++) {
                int row = (mh * 2 + m) * 16 + g * 4 + r;
                xv[m][j][r] = bf2f(s_a[row * 200 + col]) + p[m][j][r] + ap;
            }
    }
#pragma unroll
    for (int m = 0; m < 2; m++)
#pragma unroll
        for (int r = 0; r < 4; r++) {
            float s1 = xv[m][0][r] + xv[m][1][r] + xv[m][2][r];
            float s2 = xv[m][0][r] * xv[m][0][r] + xv[m][1][r] * xv[m][1][r] + xv[m][2][r] * xv[m][2][r];
            s1 += __shfl_xor(s1, 1); s1 += __shfl_xor(s1, 2); s1 += __shfl_xor(s1, 4); s1 += __shfl_xor(s1, 8);
            s2 += __shfl_xor(s2, 1); s2 += __shfl_xor(s2, 2); s2 += __shfl_xor(s2, 4); s2 += __shfl_xor(s2, 8);
            if (l16 == 0) {
                int row = (mh * 2 + m) * 16 + g * 4 + r;
                s_part[(ng * 64 + row) * 2]     = s1;
                s_part[(ng * 64 + row) * 2 + 1] = s2;
            }
        }
    __syncthreads();
    if (tid < 64) {
        float s1 = s_part[tid * 2] + s_part[(64 + tid) * 2] + s_part[(128 + tid) * 2] + s_part[(192 + tid) * 2];
        float s2 = s_part[tid * 2 + 1] + s_part[(64 + tid) * 2 + 1] + s_part[(128 + tid) * 2 + 1] + s_part[(192 + tid) * 2 + 1];
        float mu = s1 * (1.f / 192.f);
        float var = s2 * (1.f / 192.f) - mu * mu;
        s_mv[tid * 2] = mu;
        s_mv[tid * 2 + 1] = rsqrtf(var + 1e-6f);
    }
    __syncthreads();
    // ---- stage Xg-out into s_a, Ag-out into s_w8[0:12800) ----
#pragma unroll
    for (int j = 0; j < 3; j++) {
        int col = ng * 48 + j * 16 + l16;
        float lw = ln1w[col], lb = ln1b[col], ga = gamma[b * 192 + col], be = beta[b * 192 + col];
#pragma unroll
        for (int m = 0; m < 2; m++)
#pragma unroll
            for (int r = 0; r < 4; r++) {
                int row = (mh * 2 + m) * 16 + g * 4 + r;
                float x = xv[m][j][r];
                s_a[row * 200 + col] = f2bf(x);
                float xn = (x - s_mv[row * 2]) * s_mv[row * 2 + 1];
                s_w8[row * 200 + col] = f2bf((xn * lw + lb) * ga + be);
            }
    }
    __syncthreads();
#pragma unroll
    for (int t = 0; t < 3; t++) {
        int i = tid + t * TPB2;
        int flat = i << 3, row = flat / 192, col = flat - row * 192;
        *(bhalf8*)&Xg[tok0 + flat] = *(const bhalf8*)&s_a[row * 200 + col];
        *(bhalf8*)&Ag[tok0 + flat] = *(const bhalf8*)&s_w8[row * 200 + col];
    }
}

// ---------------- K3: fused cross-attention (8 waves, 1 head/wave, LDS S-tile) ----------------
__global__ __launch_bounds__(TPB2, 2) void k3_cross(
    short* __restrict__ Ag, short* __restrict__ Xg, const short* __restrict__ Sg,
    const short* __restrict__ Wqc, const short* __restrict__ Wkv,
    const short* __restrict__ Wcp, const float* __restrict__ cpb,
    const float* __restrict__ ln2w, const float* __restrict__ ln2b,
    const float* __restrict__ gamma, const float* __restrict__ beta)
{
    __shared__ short s_s[12800];       // S tile 64x200 (then Xg stage, then Xg-out)
    __shared__ short s_w8[8 * PW];
    __shared__ float s_part[512];
    __shared__ float s_mv[128];

    const int tid = threadIdx.x;
    const int wid = blockIdx.x;
    const int b = wid >> 8;
    const int w = tid >> 6;
    const int lane = tid & 63;
    const int g = lane >> 4;
    const int l16 = lane & 15;
    const int fo = lane << 3;
    const int tok0 = wid * 12288;
    short* const sq  = &s_w8[w * PW];
    short* const sk  = sq + 2560;
    short* const svt = sq + 5120;
    short* const sp  = sq;
    short* const so  = sq;
    const fvec4 z4 = {0.f, 0.f, 0.f, 0.f};

    // ---- stage SAR tile ----
#pragma unroll
    for (int t = 0; t < 3; t++) {
        int i = tid + t * TPB2;
        int flat = i << 3, row = flat / 192, col = flat - row * 192;
        *(bhalf8*)&s_s[row * 200 + col] = *(const bhalf8*)&Sg[tok0 + flat];
    }
    __syncthreads();

    {
        const int h = w;
        // ---- fused pass: Q (Ag global x Wqc), K,V (S-LDS x Wkv) ----
        fvec4 acc[4][6];   // 0,1=Q  2,3=K  4,5=V
#pragma unroll
        for (int mt = 0; mt < 4; mt++)
#pragma unroll
            for (int nt = 0; nt < 6; nt++) acc[mt][nt] = z4;
        __builtin_amdgcn_s_setprio(1);
#pragma unroll
        for (int kt = 0; kt < 6; kt++) {
            bhalf8 ag[4], sf[4];
#pragma unroll
            for (int mt = 0; mt < 4; mt++) {
                ag[mt] = *(const bhalf8*)&Ag[tok0 + (mt * 16 + l16) * 192 + kt * 32 + g * 8];
                sf[mt] = *(const bhalf8*)&s_s[(mt * 16 + l16) * 200 + kt * 32 + g * 8];
            }
#pragma unroll
            for (int nt = 0; nt < 2; nt++) {
                bhalf8 wf = *(const bhalf8*)&Wqc[((h * 12 + nt * 6 + kt) << 9) + fo];
#pragma unroll
                for (int mt = 0; mt < 4; mt++)
                    acc[mt][nt] = MFMA(ag[mt], wf, acc[mt][nt]);
            }
#pragma unroll
            for (int nt = 0; nt < 2; nt++) {
                bhalf8 wf = *(const bhalf8*)&Wkv[((h * 24 + nt * 6 + kt) << 9) + fo];
#pragma unroll
                for (int mt = 0; mt < 4; mt++)
                    acc[mt][2 + nt] = MFMA(sf[mt], wf, acc[mt][2 + nt]);
            }
#pragma unroll
            for (int nt = 0; nt < 2; nt++) {
                bhalf8 wf = *(const bhalf8*)&Wkv[((h * 24 + (nt + 2) * 6 + kt) << 9) + fo];
#pragma unroll
                for (int mt = 0; mt < 4; mt++)
                    acc[mt][4 + nt] = MFMA(sf[mt], wf, acc[mt][4 + nt]);
            }
        }
        __builtin_amdgcn_s_setprio(0);
#pragma unroll
        for (int nt = 0; nt < 6; nt++) {
            int d = (nt & 1) * 16 + l16;
#pragma unroll
            for (int mt = 0; mt < 4; mt++)
#pragma unroll
                for (int r = 0; r < 4; r++) {
                    int tok = mt * 16 + g * 4 + r;
                    short bv = f2bf(acc[mt][nt][r]);
                    if (nt < 2)      sq[tok * 40 + d] = bv;
                    else if (nt < 4) sk[tok * 40 + d] = bv;
                    else             svt[d * 72 + tok] = bv;
                }
        }
        // ---- S = Q K^T ----
        fvec4 sacc[4][4];
        {
            bhalf8 qf[4], kf[4];
#pragma unroll
            for (int mt = 0; mt < 4; mt++)
                qf[mt] = *(const bhalf8*)&sq[(mt * 16 + l16) * 40 + g * 8];
#pragma unroll
            for (int nt = 0; nt < 4; nt++)
                kf[nt] = *(const bhalf8*)&sk[(nt * 16 + l16) * 40 + g * 8];
#pragma unroll
            for (int mt = 0; mt < 4; mt++)
#pragma unroll
                for (int nt = 0; nt < 4; nt++)
                    sacc[mt][nt] = MFMA(qf[mt], kf[nt], z4);
        }
#pragma unroll
        for (int mt = 0; mt < 4; mt++) {
            float sv[4][4];
#pragma unroll
            for (int nt = 0; nt < 4; nt++)
#pragma unroll
                for (int r = 0; r < 4; r++)
                    sv[nt][r] = sacc[mt][nt][r] * SCALEF;
#pragma unroll
            for (int r = 0; r < 4; r++) {
                float m = fmaxf(fmaxf(sv[0][r], sv[1][r]), fmaxf(sv[2][r], sv[3][r]));
                m = fmaxf(m, __shfl_xor(m, 1)); m = fmaxf(m, __shfl_xor(m, 2));
                m = fmaxf(m, __shfl_xor(m, 4)); m = fmaxf(m, __shfl_xor(m, 8));
                float s = 0.f;
#pragma unroll
                for (int nt = 0; nt < 4; nt++) { sv[nt][r] = __expf(sv[nt][r] - m); s += sv[nt][r]; }
                s += __shfl_xor(s, 1); s += __shfl_xor(s, 2);
                s += __shfl_xor(s, 4); s += __shfl_xor(s, 8);
                float inv = 1.f / s;
#pragma unroll
                for (int nt = 0; nt < 4; nt++)
                    sp[(mt * 16 + g * 4 + r) * 72 + nt * 16 + l16] = f2bf(sv[nt][r] * inv);
            }
        }
        // ---- O = P V ----
        fvec4 oacc[4][2];
#pragma unroll
        for (int mt = 0; mt < 4; mt++) { oacc[mt][0] = z4; oacc[mt][1] = z4; }
#pragma unroll
        for (int ks = 0; ks < 2; ks++) {
            bhalf8 pf[4];
#pragma unroll
            for (int mt = 0; mt < 4; mt++)
                pf[mt] = *(const bhalf8*)&sp[(mt * 16 + l16) * 72 + ks * 32 + g * 8];
#pragma unroll
            for (int nt = 0; nt < 2; nt++) {
                bhalf8 vf = *(const bhalf8*)&svt[(nt * 16 + l16) * 72 + ks * 32 + g * 8];
#pragma unroll
                for (int mt = 0; mt < 4; mt++)
                    oacc[mt][nt] = MFMA(pf[mt], vf, oacc[mt][nt]);
            }
        }
#pragma unroll
        for (int nt = 0; nt < 2; nt++) {
            int d = nt * 16 + l16;
            if (d < 24) {
#pragma unroll
                for (int mt = 0; mt < 4; mt++)
#pragma unroll
                    for (int r = 0; r < 4; r++)
                        so[(mt * 16 + g * 4 + r) * 24 + d] = f2bf(oacc[mt][nt][r]);
            }
        }
    }
    __syncthreads();

    bhalf8 xst[3]; int xr[3], xc[3];
#pragma unroll
    for (int t = 0; t < 3; t++) {
        int i = tid + t * TPB2;
        int flat = i << 3; xr[t] = flat / 192; xc[t] = flat - xr[t] * 192;
        xst[t] = *(const bhalf8*)&Xg[tok0 + flat];
    }

    const int mh = w & 1, ng = w >> 1;
    fvec4 p[2][3];
#pragma unroll
    for (int m = 0; m < 2; m++)
#pragma unroll
        for (int j = 0; j < 3; j++) p[m][j] = z4;
#pragma unroll
    for (int kt = 0; kt < 6; kt++) {
        int c0 = kt * 32 + g * 8;
        int h0 = c0 / 24, d0 = c0 - h0 * 24;
        bhalf8 of[2];
#pragma unroll
        for (int m = 0; m < 2; m++)
            of[m] = *(const bhalf8*)&s_w8[h0 * PW + ((mh * 2 + m) * 16 + l16) * 24 + d0];
#pragma unroll
        for (int j = 0; j < 3; j++) {
            bhalf8 wf = *(const bhalf8*)&Wcp[(((ng * 3 + j) * 6 + kt) << 9) + fo];
#pragma unroll
            for (int m = 0; m < 2; m++)
                p[m][j] = MFMA(of[m], wf, p[m][j]);
        }
    }
#pragma unroll
    for (int t = 0; t < 3; t++)
        *(bhalf8*)&s_s[xr[t] * 200 + xc[t]] = xst[t];
    __syncthreads();

    float xv[2][3][4];
#pragma unroll
    for (int j = 0; j < 3; j++) {
        int col = ng * 48 + j * 16 + l16;
        float cp = cpb[col];
#pragma unroll
        for (int m = 0; m < 2; m++)
#pragma unroll
            for (int r = 0; r < 4; r++) {
                int row = (mh * 2 + m) * 16 + g * 4 + r;
                xv[m][j][r] = bf2f(s_s[row * 200 + col]) + p[m][j][r] + cp;
            }
    }
#pragma unroll
    for (int m = 0; m < 2; m++)
#pragma unroll
        for (int r = 0; r < 4; r++) {
            float s1 = xv[m][0][r] + xv[m][1][r] + xv[m][2][r];
            float s2 = xv[m][0][r] * xv[m][0][r] + xv[m][1][r] * xv[m][1][r] + xv[m][2][r] * xv[m][2][r];
            s1 += __shfl_xor(s1, 1); s1 += __shfl_xor(s1, 2); s1 += __shfl_xor(s1, 4); s1 += __shfl_xor(s1, 8);
            s2 += __shfl_xor(s2, 1); s2 += __shfl_xor(s2, 2); s2 += __shfl_xor(s2, 4); s2 += __shfl_xor(s2, 8);
            if (l16 == 0) {
                int row = (mh * 2 + m) * 16 + g * 4 + r;
                s_part[(ng * 64 + row) * 2]     = s1;
                s_part[(ng * 64 + row) * 2 + 1] = s2;
            }
        }
    __syncthreads();
    if (tid < 64) {
        float s1 = s_part[tid * 2] + s_part[(64 + tid) * 2] + s_part[(128 + tid) * 2] + s_part[(192 + tid) * 2];
        float s2 = s_part[tid * 2 + 1] + s_part[(64 + tid) * 2 + 1] + s_part[(128 + tid) * 2 + 1] + s_part[(192 + tid) * 2 + 1];
        float mu = s1 * (1.f / 192.f);
        float var = s2 * (1.f / 192.f) - mu * mu;
        s_mv[tid * 2] = mu;
        s_mv[tid * 2 + 1] = rsqrtf(var + 1e-6f);
    }
    __syncthreads();
#pragma unroll
    for (int j = 0; j < 3; j++) {
        int col = ng * 48 + j * 16 + l16;
        float lw = ln2w[col], lb = ln2b[col], ga = gamma[b * 192 + col], be = beta[b * 192 + col];
#pragma unroll
        for (int m = 0; m < 2; m++)
#pragma unroll
            for (int r = 0; r < 4; r++) {
                int row = (mh * 2 + m) * 16 + g * 4 + r;
                float x = xv[m][j][r];
                s_s[row * 200 + col] = f2bf(x);
                float xn = (x - s_mv[row * 2]) * s_mv[row * 2 + 1];
                s_w8[row * 200 + col] = f2bf((xn * lw + lb) * ga + be);
            }
    }
    __syncthreads();
#pragma unroll
    for (int t = 0; t < 3; t++) {
        int i = tid + t * TPB2;
        int flat = i << 3, row = flat / 192, col = flat - row * 192;
        *(bhalf8*)&Xg[tok0 + flat] = *(const bhalf8*)&s_s[row * 200 + col];
        *(bhalf8*)&Ag[tok0 + flat] = *(const bhalf8*)&s_w8[row * 200 + col];
    }
}

// ---------------- K4: fused FFN + residual, scatter to NCHW ----------------
__global__ __launch_bounds__(TPB) void k4_ffn(
    const short* __restrict__ Ag, const short* __restrict__ Xg,
    const short* __restrict__ W1b, const short* __restrict__ W2b,
    float* __restrict__ out)
{
    __shared__ short s_u[12800];
    __shared__ short s_h[12800];

    const int tid = threadIdx.x;
    const int wid = blockIdx.x;
    const int b = wid >> 8, hb = (wid >> 4) & 15, wb = wid & 15;
    const int xbase = ((b * 192) << 14) + ((hb * 8) << 7) + wb * 8;
    const int w = tid >> 6;
    const int lane = tid & 63;
    const int g = lane >> 4;
    const int l16 = lane & 15;
    const int fo = lane << 3;
    const int tok0 = wid * 12288;
    const fvec4 z4 = {0.f, 0.f, 0.f, 0.f};

    for (int i = tid; i < 1536; i += TPB) {
        int flat = i << 3;
        int t = flat / 192, cc = flat - t * 192;
        *(bhalf8*)&s_u[t * 200 + cc] = *(const bhalf8*)&Ag[tok0 + flat];
    }
    // ---- prefetch Xg residual into regs (consumed after the chunk loop) ----
    bhalf8 xpre[6];
#pragma unroll
    for (int t6 = 0; t6 < 6; t6++)
        xpre[t6] = *(const bhalf8*)&Xg[tok0 + ((tid + t6 * TPB) << 3)];
    __syncthreads();

    fvec4 yacc[4][3];
#pragma unroll
    for (int mt = 0; mt < 4; mt++)
#pragma unroll
        for (int j = 0; j < 3; j++) yacc[mt][j] = z4;

    for (int c = 0; c < 6; c++) {
        fvec4 hacc[4][2];
#pragma unroll
        for (int mt = 0; mt < 4; mt++) { hacc[mt][0] = z4; hacc[mt][1] = z4; }
#pragma unroll
        for (int kt = 0; kt < 6; kt++) {
            bhalf8 af[4];
#pragma unroll
            for (int mt = 0; mt < 4; mt++)
                af[mt] = *(const bhalf8*)&s_u[(mt * 16 + l16) * 200 + kt * 32 + g * 8];
#pragma unroll
            for (int n2 = 0; n2 < 2; n2++) {
                bhalf8 wf = *(const bhalf8*)&W1b[(((c * 8 + w * 2 + n2) * 6 + kt) << 9) + fo];
#pragma unroll
                for (int mt = 0; mt < 4; mt++)
                    hacc[mt][n2] = MFMA(af[mt], wf, hacc[mt][n2]);
            }
        }
        // ---- GELU (sigmoid form; |err vs erf-GELU| < 3e-4, well under bf16 rounding) ----
#pragma unroll
        for (int n2 = 0; n2 < 2; n2++) {
            int cc = w * 32 + n2 * 16 + l16;
#pragma unroll
            for (int mt = 0; mt < 4; mt++) {
#pragma unroll
                for (int r = 0; r < 4; r++) {
                    float x = hacc[mt][n2][r];
                    float z = 1.5957691216f * x * (1.f + 0.044715f * x * x);
                    float gl = x / (1.f + __expf(-z));
                    s_h[(mt * 16 + g * 4 + r) * 200 + cc] = f2bf(gl);
                }
            }
        }
        __syncthreads();
#pragma unroll
        for (int ks = 0; ks < 4; ks++) {
            bhalf8 hf[4];
#pragma unroll
            for (int mt = 0; mt < 4; mt++)
                hf[mt] = *(const bhalf8*)&s_h[(mt * 16 + l16) * 200 + ks * 32 + g * 8];
#pragma unroll
            for (int j = 0; j < 3; j++) {
                bhalf8 wf = *(const bhalf8*)&W2b[(((w * 3 + j) * 24 + c * 4 + ks) << 9) + fo];
#pragma unroll
                for (int mt = 0; mt < 4; mt++)
                    yacc[mt][j] = MFMA(hf[mt], wf, yacc[mt][j]);
            }
        }
        __syncthreads();
    }

    // ---- write prefetched Xg into s_h ----
#pragma unroll
    for (int t6 = 0; t6 < 6; t6++) {
        int i = tid + t6 * TPB;
        int flat = i << 3;
        int t = flat / 192, cc = flat - t * 192;
        *(bhalf8*)&s_h[t * 200 + cc] = xpre[t6];
    }
    __syncthreads();
#pragma unroll
    for (int j = 0; j < 3; j++) {
        int col = (w * 3 + j) * 16 + l16;
#pragma unroll
        for (int mt = 0; mt < 4; mt++) {
#pragma unroll
            for (int r = 0; r < 4; r++) {
                int tok = mt * 16 + g * 4 + r;
                float v = bf2f(s_h[tok * 200 + col]) + yacc[mt][j][r];
                s_u[tok * 200 + col] = f2bf(v);
            }
        }
    }
    __syncthreads();
    // ---- vectorized float4 scatter to NCHW ----
    for (int i = tid; i < 3072; i += TPB) {
        int cc = i >> 4, rem = i & 15, hrow = rem >> 1, half = rem & 1;
        int l0 = hrow * 8 + half * 4;
        float4 v;
        v.x = bf2f(s_u[(l0 + 0) * 200 + cc]);
        v.y = bf2f(s_u[(l0 + 1) * 200 + cc]);
        v.z = bf2f(s_u[(l0 + 2) * 200 + cc]);
        v.w = bf2f(s_u[(l0 + 3) * 200 + cc]);
        *(float4*)&out[xbase + (cc << 14) + (hrow << 7) + half * 4] = v;
    }
}

extern "C" void kernel_launch(void* const* d_in, const int* in_sizes, int n_in,
                              void* d_out, int out_size, void* d_ws, size_t ws_size,
                              hipStream_t stream) {
    const float* xrgb  = (const float*)d_in[0];
    const float* xsar  = (const float*)d_in[1];
    const float* gamma = (const float*)d_in[2];
    const float* beta  = (const float*)d_in[3];
    const float* ln1w  = (const float*)d_in[4];
    const float* ln1b  = (const float*)d_in[5];
    const float* ln2w  = (const float*)d_in[6];
    const float* ln2b  = (const float*)d_in[7];
    const float* qkvw  = (const float*)d_in[8];
    const float* qkvb  = (const float*)d_in[9];
    const float* apw   = (const float*)d_in[10];
    const float* apb   = (const float*)d_in[11];
    const float* relb  = (const float*)d_in[12];
    const float* qw    = (const float*)d_in[13];
    const float* kvw   = (const float*)d_in[14];
    const float* cpw   = (const float*)d_in[15];
    const float* cpb   = (const float*)d_in[16];
    const float* w1    = (const float*)d_in[17];
    const float* w2    = (const float*)d_in[18];

    char* base = (char*)d_ws;
    short* Wqkv = (short*)base;
    short* Wqc  = Wqkv + N_QKV;
    short* Wkv  = Wqc + N_QC;
    short* Wap  = Wkv + N_KV;
    short* Wcp  = Wap + N_AP;
    short* W1b  = Wcp + N_CP;
    short* W2b  = W1b + N_W1;
    float* qbp  = (float*)(base + (size_t)W_TOT * 2);          // 768 floats
    short* Ag   = (short*)(base + (size_t)W_TOT * 2 + 3072);   // 131072 x 192 bf16
    short* Xg   = Ag + 25165824;
    short* Sg   = Xg + 25165824;

    float* out = (float*)d_out;

    hipLaunchKernelGGL(k0_wprep, dim3(256), dim3(TPB), 0, stream,
                       qkvw, qkvb, qw, kvw, apw, cpw, w1, w2,
                       Wqkv, Wqc, Wkv, Wap, Wcp, W1b, W2b, qbp);
    hipLaunchKernelGGL(k1_prep, dim3(NWIN), dim3(TPB), 0, stream,
                       xrgb, xsar, gamma, beta, ln1w, ln1b, Ag, Xg, Sg);
    hipLaunchKernelGGL(k2_self, dim3(NWIN), dim3(TPB2), 0, stream,
                       Ag, Xg, Wqkv, qbp, Wap, apb, relb, ln1w, ln1b, gamma, beta);
    hipLaunchKernelGGL(k3_cross, dim3(NWIN), dim3(TPB2), 0, stream,
                       Ag, Xg, Sg, Wqc, Wkv, Wcp, cpb, ln2w, ln2b, gamma, beta);
    hipLaunchKernelGGL(k4_ffn, dim3(NWIN), dim3(TPB), 0, stream,
                       Ag, Xg, W1b, W2b, out);
}

// Round 5
// 897.648 us; speedup vs baseline: 1.0902x; 1.0902x over previous
//
#include <hip/hip_runtime.h>
#include <math.h>

// FusionRestormerBlock — bf16 MFMA, fragment-ordered weights.
// v6: k4 rebuilt for TLP — 512 threads / 8 waves, finer N-split (GEMM1: 1
// hidden tile/wave; GEMM2: 32-row x 3-tile patch/wave), LDS 43KB -> 3
// blocks/CU (target 6 waves/SIMD). k4 was running ~10x its issue floor at
// 2 waves/SIMD (latency-bound, round-4 post-mortem). k1/k2/k3 from v5.

#define TPB 256
#define TPB2 512
#define NWIN 2048
#define SCALEF 0.20412414523193154f  // 24^-0.5

typedef __attribute__((ext_vector_type(8))) short bhalf8;
typedef __attribute__((ext_vector_type(4))) float fvec4;

#define MFMA(a, b, c) __builtin_amdgcn_mfma_f32_16x16x32_bf16(a, b, c, 0, 0, 0)

__device__ __forceinline__ short f2bf(float f) {
    unsigned u = __float_as_uint(f);
    u = u + 0x7fffu + ((u >> 16) & 1u);
    return (short)(u >> 16);
}
__device__ __forceinline__ float bf2f(short s) {
    return __uint_as_float(((unsigned)(unsigned short)s) << 16);
}

// Weight region element counts (bf16 elements), all tile-packed
#define N_QKV 147456     // 8 heads x (6 nt x 6 kt) tiles
#define N_QC  49152      // 8 x (2 x 6)
#define N_KV  98304      // 8 x (4 x 6)
#define N_AP  36864      // 12 x 6
#define N_CP  36864
#define N_W1  147456     // 48 x 6
#define N_W2  147456     // 12 nt x 24 ks
#define W_TOT 663552

// per-wave LDS region (shorts): q[0:2560) k[2560:5120) vt[5120:7424)
#define PW 7424

// ---------------- K0: weight prep (fp32 -> padded bf16, fragment-tile order) ----------------
__global__ __launch_bounds__(TPB) void k0_wprep(
    const float* __restrict__ qkvw, const float* __restrict__ qkvb,
    const float* __restrict__ qw, const float* __restrict__ kvw,
    const float* __restrict__ apw, const float* __restrict__ cpw,
    const float* __restrict__ w1, const float* __restrict__ w2,
    short* __restrict__ Wqkv, short* __restrict__ Wqc, short* __restrict__ Wkv,
    short* __restrict__ Wap, short* __restrict__ Wcp, short* __restrict__ W1b,
    short* __restrict__ W2b, float* __restrict__ qbp)
{
    const int tid = blockIdx.x * TPB + threadIdx.x;
    const int stride = gridDim.x * TPB;
    for (int i = tid; i < N_QKV; i += stride) {
        int tile = i >> 9, pos = i & 511;
        int lane = pos >> 3, j = pos & 7, l16 = lane & 15, g = lane >> 4;
        int h = tile / 36, t2 = tile % 36, nt = t2 / 6, kt = t2 % 6;
        int col = nt * 16 + l16, sub = col >> 5, d = col & 31;
        int k = kt * 32 + g * 8 + j;
        float v = (d < 24) ? qkvw[(sub * 192 + h * 24 + d) * 192 + k] : 0.f;
        Wqkv[i] = f2bf(v);
    }
    for (int i = tid; i < N_QC; i += stride) {
        int tile = i >> 9, pos = i & 511;
        int lane = pos >> 3, j = pos & 7, l16 = lane & 15, g = lane >> 4;
        int h = tile / 12, t2 = tile % 12, nt = t2 / 6, kt = t2 % 6;
        int col = nt * 16 + l16;
        int k = kt * 32 + g * 8 + j;
        float v = (col < 24) ? qw[(h * 24 + col) * 192 + k] : 0.f;
        Wqc[i] = f2bf(v);
    }
    for (int i = tid; i < N_KV; i += stride) {
        int tile = i >> 9, pos = i & 511;
        int lane = pos >> 3, j = pos & 7, l16 = lane & 15, g = lane >> 4;
        int h = tile / 24, t2 = tile % 24, nt = t2 / 6, kt = t2 % 6;
        int col = nt * 16 + l16, sub = col >> 5, d = col & 31;
        int k = kt * 32 + g * 8 + j;
        float v = (d < 24) ? kvw[(sub * 192 + h * 24 + d) * 192 + k] : 0.f;
        Wkv[i] = f2bf(v);
    }
    for (int i = tid; i < N_AP; i += stride) {
        int tile = i >> 9, pos = i & 511;
        int lane = pos >> 3, j = pos & 7, l16 = lane & 15, g = lane >> 4;
        int nt = tile / 6, kt = tile % 6;
        int n = nt * 16 + l16, k = kt * 32 + g * 8 + j;
        Wap[i] = f2bf(apw[n * 192 + k]);
    }
    for (int i = tid; i < N_CP; i += stride) {
        int tile = i >> 9, pos = i & 511;
        int lane = pos >> 3, j = pos & 7, l16 = lane & 15, g = lane >> 4;
        int nt = tile / 6, kt = tile % 6;
        int n = nt * 16 + l16, k = kt * 32 + g * 8 + j;
        Wcp[i] = f2bf(cpw[n * 192 + k]);
    }
    for (int i = tid; i < N_W1; i += stride) {
        int tile = i >> 9, pos = i & 511;
        int lane = pos >> 3, j = pos & 7, l16 = lane & 15, g = lane >> 4;
        int nt = tile / 6, kt = tile % 6;
        int n = nt * 16 + l16, k = kt * 32 + g * 8 + j;
        W1b[i] = f2bf(w1[n * 192 + k]);
    }
    for (int i = tid; i < N_W2; i += stride) {
        int tile = i >> 9, pos = i & 511;
        int lane = pos >> 3, j = pos & 7, l16 = lane & 15, g = lane >> 4;
        int nt = tile / 24, ks = tile % 24;
        int n = nt * 16 + l16, k = ks * 32 + g * 8 + j;
        W2b[i] = f2bf(w2[n * 768 + k]);
    }
    for (int i = tid; i < 768; i += stride) {
        int h = i / 96, col = i % 96, sub = col >> 5, d = col & 31;
        qbp[i] = (d < 24) ? qkvb[sub * 192 + h * 24 + d] : 0.f;
    }
}

// ---------------- K1: tokenize + cln1 (vectorized IO) ----------------
__global__ __launch_bounds__(TPB) void k1_prep(
    const float* __restrict__ xrgb, const float* __restrict__ xsar,
    const float* __restrict__ gamma, const float* __restrict__ beta,
    const float* __restrict__ ln1w, const float* __restrict__ ln1b,
    short* __restrict__ Ag, short* __restrict__ Xg, short* __restrict__ Sg)
{
    __shared__ float s_x[64 * 193];
    __shared__ float s_mu[64], s_rs[64];
    __shared__ float s_cw[768];   // ln1w | ln1b | gamma_b | beta_b
    const int tid = threadIdx.x;
    const int wid = blockIdx.x;
    const int b = wid >> 8, hb = (wid >> 4) & 15, wb = wid & 15;
    const int xbase = ((b * 192) << 14) + ((hb * 8) << 7) + wb * 8;
    const int tok0 = wid * 12288;

    for (int i = tid; i < 192; i += TPB) {
        s_cw[i]       = ln1w[i];
        s_cw[192 + i] = ln1b[i];
        s_cw[384 + i] = gamma[b * 192 + i];
        s_cw[576 + i] = beta[b * 192 + i];
    }
    // ---- float4 loads: 192 c x 8 hrow x 2 half ----
    for (int i = tid; i < 3072; i += TPB) {
        int c = i >> 4, rem = i & 15, hrow = rem >> 1, half = rem & 1;
        float4 v = *(const float4*)&xrgb[xbase + (c << 14) + (hrow << 7) + half * 4];
        int l = hrow * 8 + half * 4;
        s_x[(l + 0) * 193 + c] = v.x;
        s_x[(l + 1) * 193 + c] = v.y;
        s_x[(l + 2) * 193 + c] = v.z;
        s_x[(l + 3) * 193 + c] = v.w;
    }
    __syncthreads();
    {
        int t = tid >> 2, q4 = tid & 3;
        float sum = 0.f, sq = 0.f;
        for (int j = 0; j < 48; j++) {
            float v = s_x[t * 193 + q4 * 48 + j];
            sum += v; sq += v * v;
        }
        sum += __shfl_xor(sum, 1); sum += __shfl_xor(sum, 2);
        sq  += __shfl_xor(sq, 1);  sq  += __shfl_xor(sq, 2);
        float mu = sum * (1.f / 192.f);
        float var = sq * (1.f / 192.f) - mu * mu;
        if (q4 == 0) { s_mu[t] = mu; s_rs[t] = rsqrtf(var + 1e-6f); }
    }
    __syncthreads();
    // ---- packed bhalf8 stores ----
    for (int i = tid; i < 1536; i += TPB) {
        int flat = i << 3, t = flat / 192, c0 = flat - t * 192;
        float mu = s_mu[t], rs = s_rs[t];
        bhalf8 xv, av;
#pragma unroll
        for (int j = 0; j < 8; j++) {
            float x = s_x[t * 193 + c0 + j];
            xv[j] = f2bf(x);
            float xn = (x - mu) * rs;
            av[j] = f2bf((xn * s_cw[c0 + j] + s_cw[192 + c0 + j]) * s_cw[384 + c0 + j] + s_cw[576 + c0 + j]);
        }
        *(bhalf8*)&Xg[tok0 + flat] = xv;
        *(bhalf8*)&Ag[tok0 + flat] = av;
    }
    __syncthreads();
    for (int i = tid; i < 3072; i += TPB) {
        int c = i >> 4, rem = i & 15, hrow = rem >> 1, half = rem & 1;
        float4 v = *(const float4*)&xsar[xbase + (c << 14) + (hrow << 7) + half * 4];
        int l = hrow * 8 + half * 4;
        s_x[(l + 0) * 193 + c] = v.x;
        s_x[(l + 1) * 193 + c] = v.y;
        s_x[(l + 2) * 193 + c] = v.z;
        s_x[(l + 3) * 193 + c] = v.w;
    }
    __syncthreads();
    for (int i = tid; i < 1536; i += TPB) {
        int flat = i << 3, t = flat / 192, c0 = flat - t * 192;
        bhalf8 sv;
#pragma unroll
        for (int j = 0; j < 8; j++) sv[j] = f2bf(s_x[t * 193 + c0 + j]);
        *(bhalf8*)&Sg[tok0 + flat] = sv;
    }
}

// ---------------- K2: fused self-attention (8 waves, 1 head/wave, LDS A-tile) ----------------
__global__ __launch_bounds__(TPB2, 2) void k2_self(
    short* __restrict__ Ag, short* __restrict__ Xg,
    const short* __restrict__ Wqkv, const float* __restrict__ qbp,
    const short* __restrict__ Wap, const float* __restrict__ apb,
    const float* __restrict__ relb,
    const float* __restrict__ ln1w, const float* __restrict__ ln1b,
    const float* __restrict__ gamma, const float* __restrict__ beta)
{
    __shared__ short s_a[12800];       // A tile 64x200 (then Xg stage, then Xg-out)
    __shared__ short s_w8[8 * PW];     // per-wave q/k/vt (sp,O overlay); then Ag-out [0:12800)
    __shared__ short s_rb[1800];
    __shared__ float s_part[512];      // [ng:4][row:64][2]
    __shared__ float s_mv[128];        // [row][mu,rs]

    const int tid = threadIdx.x;
    const int wid = blockIdx.x;
    const int b = wid >> 8;
    const int w = tid >> 6;            // wave 0..7 = head
    const int lane = tid & 63;
    const int g = lane >> 4;
    const int l16 = lane & 15;
    const int fo = lane << 3;
    const int tok0 = wid * 12288;
    short* const sq  = &s_w8[w * PW];
    short* const sk  = sq + 2560;
    short* const svt = sq + 5120;
    short* const sp  = sq;             // overlays q/k
    short* const so  = sq;             // O stash overlays sp after PV
    const fvec4 z4 = {0.f, 0.f, 0.f, 0.f};

    // ---- stage A tile (vectorized) + rel bias ----
#pragma unroll
    for (int t = 0; t < 3; t++) {
        int i = tid + t * TPB2;
        int flat = i << 3, row = flat / 192, col = flat - row * 192;
        *(bhalf8*)&s_a[row * 200 + col] = *(const bhalf8*)&Ag[tok0 + flat];
    }
    for (int i = tid; i < 1800; i += TPB2) s_rb[i] = f2bf(relb[i]);
    __syncthreads();

    {
        const int h = w;
        // ---- fused QKV GEMM (one pass, A from LDS) ----
        fvec4 acc[4][6];
#pragma unroll
        for (int mt = 0; mt < 4; mt++)
#pragma unroll
            for (int nt = 0; nt < 6; nt++) acc[mt][nt] = z4;
        __builtin_amdgcn_s_setprio(1);
#pragma unroll
        for (int kt = 0; kt < 6; kt++) {
            bhalf8 af[4];
#pragma unroll
            for (int mt = 0; mt < 4; mt++)
                af[mt] = *(const bhalf8*)&s_a[(mt * 16 + l16) * 200 + kt * 32 + g * 8];
#pragma unroll
            for (int nt = 0; nt < 6; nt++) {
                bhalf8 wf = *(const bhalf8*)&Wqkv[((h * 36 + nt * 6 + kt) << 9) + fo];
#pragma unroll
                for (int mt = 0; mt < 4; mt++)
                    acc[mt][nt] = MFMA(af[mt], wf, acc[mt][nt]);
            }
        }
        __builtin_amdgcn_s_setprio(0);
        // write Q (nt 0,1), K (nt 2,3), V^T (nt 4,5); pads d 24..31 are exact zeros
#pragma unroll
        for (int nt = 0; nt < 6; nt++) {
            float bq = qbp[h * 96 + nt * 16 + l16];
            int d = (nt & 1) * 16 + l16;
#pragma unroll
            for (int mt = 0; mt < 4; mt++)
#pragma unroll
                for (int r = 0; r < 4; r++) {
                    int tok = mt * 16 + g * 4 + r;
                    short bv = f2bf(acc[mt][nt][r] + bq);
                    if (nt < 2)      sq[tok * 40 + d] = bv;
                    else if (nt < 4) sk[tok * 40 + d] = bv;
                    else             svt[d * 72 + tok] = bv;
                }
        }
        // ---- S = Q K^T (wave-local) ----
        fvec4 sacc[4][4];
        {
            bhalf8 qf[4], kf[4];
#pragma unroll
            for (int mt = 0; mt < 4; mt++)
                qf[mt] = *(const bhalf8*)&sq[(mt * 16 + l16) * 40 + g * 8];
#pragma unroll
            for (int nt = 0; nt < 4; nt++)
                kf[nt] = *(const bhalf8*)&sk[(nt * 16 + l16) * 40 + g * 8];
#pragma unroll
            for (int mt = 0; mt < 4; mt++)
#pragma unroll
                for (int nt = 0; nt < 4; nt++)
                    sacc[mt][nt] = MFMA(qf[mt], kf[nt], z4);
        }
        // ---- softmax, P -> sp ----
#pragma unroll
        for (int mt = 0; mt < 4; mt++) {
            float sv[4][4];
#pragma unroll
            for (int nt = 0; nt < 4; nt++) {
                int n = nt * 16 + l16, ki = n >> 3, kj = n & 7;
#pragma unroll
                for (int r = 0; r < 4; r++) {
                    int qq = mt * 16 + g * 4 + r, qi = qq >> 3, qj = qq & 7;
                    int ridx = (qi - ki + 7) * 15 + (qj - kj + 7);
                    sv[nt][r] = sacc[mt][nt][r] * SCALEF + bf2f(s_rb[ridx * 8 + h]);
                }
            }
#pragma unroll
            for (int r = 0; r < 4; r++) {
                float m = fmaxf(fmaxf(sv[0][r], sv[1][r]), fmaxf(sv[2][r], sv[3][r]));
                m = fmaxf(m, __shfl_xor(m, 1)); m = fmaxf(m, __shfl_xor(m, 2));
                m = fmaxf(m, __shfl_xor(m, 4)); m = fmaxf(m, __shfl_xor(m, 8));
                float s = 0.f;
#pragma unroll
                for (int nt = 0; nt < 4; nt++) { sv[nt][r] = __expf(sv[nt][r] - m); s += sv[nt][r]; }
                s += __shfl_xor(s, 1); s += __shfl_xor(s, 2);
                s += __shfl_xor(s, 4); s += __shfl_xor(s, 8);
                float inv = 1.f / s;
#pragma unroll
                for (int nt = 0; nt < 4; nt++)
                    sp[(mt * 16 + g * 4 + r) * 72 + nt * 16 + l16] = f2bf(sv[nt][r] * inv);
            }
        }
        // ---- O = P V ----
        fvec4 oacc[4][2];
#pragma unroll
        for (int mt = 0; mt < 4; mt++) { oacc[mt][0] = z4; oacc[mt][1] = z4; }
#pragma unroll
        for (int ks = 0; ks < 2; ks++) {
            bhalf8 pf[4];
#pragma unroll
            for (int mt = 0; mt < 4; mt++)
                pf[mt] = *(const bhalf8*)&sp[(mt * 16 + l16) * 72 + ks * 32 + g * 8];
#pragma unroll
            for (int nt = 0; nt < 2; nt++) {
                bhalf8 vf = *(const bhalf8*)&svt[(nt * 16 + l16) * 72 + ks * 32 + g * 8];
#pragma unroll
                for (int mt = 0; mt < 4; mt++)
                    oacc[mt][nt] = MFMA(pf[mt], vf, oacc[mt][nt]);
            }
        }
        // ---- stash O [tok][24] in own region ----
#pragma unroll
        for (int nt = 0; nt < 2; nt++) {
            int d = nt * 16 + l16;
            if (d < 24) {
#pragma unroll
                for (int mt = 0; mt < 4; mt++)
#pragma unroll
                    for (int r = 0; r < 4; r++)
                        so[(mt * 16 + g * 4 + r) * 24 + d] = f2bf(oacc[mt][nt][r]);
            }
        }
    }
    __syncthreads();

    // ---- prefetch Xg residual into registers (hides under proj) ----
    bhalf8 xst[3]; int xr[3], xc[3];
#pragma unroll
    for (int t = 0; t < 3; t++) {
        int i = tid + t * TPB2;
        int flat = i << 3; xr[t] = flat / 192; xc[t] = flat - xr[t] * 192;
        xst[t] = *(const bhalf8*)&Xg[tok0 + flat];
    }

    // ---- proj: wave = (mh = w&1: rows mh*32..+32) x (ng = w>>1: cols ng*48..+48) ----
    const int mh = w & 1, ng = w >> 1;
    fvec4 p[2][3];
#pragma unroll
    for (int m = 0; m < 2; m++)
#pragma unroll
        for (int j = 0; j < 3; j++) p[m][j] = z4;
#pragma unroll
    for (int kt = 0; kt < 6; kt++) {
        int c0 = kt * 32 + g * 8;
        int h0 = c0 / 24, d0 = c0 - h0 * 24;
        bhalf8 of[2];
#pragma unroll
        for (int m = 0; m < 2; m++)
            of[m] = *(const bhalf8*)&s_w8[h0 * PW + ((mh * 2 + m) * 16 + l16) * 24 + d0];
#pragma unroll
        for (int j = 0; j < 3; j++) {
            bhalf8 wf = *(const bhalf8*)&Wap[(((ng * 3 + j) * 6 + kt) << 9) + fo];
#pragma unroll
            for (int m = 0; m < 2; m++)
                p[m][j] = MFMA(of[m], wf, p[m][j]);
        }
    }
    // ---- write Xg stage to s_a (A tile dead) ----
#pragma unroll
    for (int t = 0; t < 3; t++)
        *(bhalf8*)&s_a[xr[t] * 200 + xc[t]] = xst[t];
    __syncthreads();

    // ---- x1 = x_rgb + y + apb ; cross-wave LN ----
    float xv[2][3][4];
#pragma unroll
    for (int j = 0; j < 3; j++) {
        int col = ng * 48 + j * 16 + l16;
        float ap = apb[col];
#pragma unroll
        for (int m = 0; m < 2; m++)
#pragma unroll
            for (int r = 0; r < 4; r++) {
                int row = (mh * 2 + m) * 16 + g * 4 + r;
                xv[m][j][r] = bf2f(s_a[row * 200 + col]) + p[m][j][r] + ap;
            }
    }
#pragma unroll
    for (int m = 0; m < 2; m++)
#pragma unroll
        for (int r = 0; r < 4; r++) {
            float s1 = xv[m][0][r] + xv[m][1][r] + xv[m][2][r];
            float s2 = xv[m][0][r] * xv[m][0][r] + xv[m][1][r] * xv[m][1][r] + xv[m][2][r] * xv[m][2][r];
            s1 += __shfl_xor(s1, 1); s1 += __shfl_xor(s1, 2); s1 += __shfl_xor(s1, 4); s1 += __shfl_xor(s1, 8);
            s2 += __shfl_xor(s2, 1); s2 += __shfl_xor(s2, 2); s2 += __shfl_xor(s2, 4); s2 += __shfl_xor(s2, 8);
            if (l16 == 0) {
                int row = (mh * 2 + m) * 16 + g * 4 + r;
                s_part[(ng * 64 + row) * 2]     = s1;
                s_part[(ng * 64 + row) * 2 + 1] = s2;
            }
        }
    __syncthreads();
    if (tid < 64) {
        float s1 = s_part[tid * 2] + s_part[(64 + tid) * 2] + s_part[(128 + tid) * 2] + s_part[(192 + tid) * 2];
        float s2 = s_part[tid * 2 + 1] + s_part[(64 + tid) * 2 + 1] + s_part[(128 + tid) * 2 + 1] + s_part[(192 + tid) * 2 + 1];
        float mu = s1 * (1.f / 192.f);
        float var = s2 * (1.f / 192.f) - mu * mu;
        s_mv[tid * 2] = mu;
        s_mv[tid * 2 + 1] = rsqrtf(var + 1e-6f);
    }
    __syncthreads();
    // ---- stage Xg-out into s_a, Ag-out into s_w8[0:12800) ----
#pragma unroll
    for (int j = 0; j < 3; j++) {
        int col = ng * 48 + j * 16 + l16;
        float lw = ln1w[col], lb = ln1b[col], ga = gamma[b * 192 + col], be = beta[b * 192 + col];
#pragma unroll
        for (int m = 0; m < 2; m++)
#pragma unroll
            for (int r = 0; r < 4; r++) {
                int row = (mh * 2 + m) * 16 + g * 4 + r;
                float x = xv[m][j][r];
                s_a[row * 200 + col] = f2bf(x);
                float xn = (x - s_mv[row * 2]) * s_mv[row * 2 + 1];
                s_w8[row * 200 + col] = f2bf((xn * lw + lb) * ga + be);
            }
    }
    __syncthreads();
#pragma unroll
    for (int t = 0; t < 3; t++) {
        int i = tid + t * TPB2;
        int flat = i << 3, row = flat / 192, col = flat - row * 192;
        *(bhalf8*)&Xg[tok0 + flat] = *(const bhalf8*)&s_a[row * 200 + col];
        *(bhalf8*)&Ag[tok0 + flat] = *(const bhalf8*)&s_w8[row * 200 + col];
    }
}

// ---------------- K3: fused cross-attention (8 waves, 1 head/wave, LDS S-tile) ----------------
__global__ __launch_bounds__(TPB2, 2) void k3_cross(
    short* __restrict__ Ag, short* __restrict__ Xg, const short* __restrict__ Sg,
    const short* __restrict__ Wqc, const short* __restrict__ Wkv,
    const short* __restrict__ Wcp, const float* __restrict__ cpb,
    const float* __restrict__ ln2w, const float* __restrict__ ln2b,
    const float* __restrict__ gamma, const float* __restrict__ beta)
{
    __shared__ short s_s[12800];       // S tile 64x200 (then Xg stage, then Xg-out)
    __shared__ short s_w8[8 * PW];
    __shared__ float s_part[512];
    __shared__ float s_mv[128];

    const int tid = threadIdx.x;
    const int wid = blockIdx.x;
    const int b = wid >> 8;
    const int w = tid >> 6;
    const int lane = tid & 63;
    const int g = lane >> 4;
    const int l16 = lane & 15;
    const int fo = lane << 3;
    const int tok0 = wid * 12288;
    short* const sq  = &s_w8[w * PW];
    short* const sk  = sq + 2560;
    short* const svt = sq + 5120;
    short* const sp  = sq;
    short* const so  = sq;
    const fvec4 z4 = {0.f, 0.f, 0.f, 0.f};

    // ---- stage SAR tile ----
#pragma unroll
    for (int t = 0; t < 3; t++) {
        int i = tid + t * TPB2;
        int flat = i << 3, row = flat / 192, col = flat - row * 192;
        *(bhalf8*)&s_s[row * 200 + col] = *(const bhalf8*)&Sg[tok0 + flat];
    }
    __syncthreads();

    {
        const int h = w;
        // ---- fused pass: Q (Ag global x Wqc), K,V (S-LDS x Wkv) ----
        fvec4 acc[4][6];   // 0,1=Q  2,3=K  4,5=V
#pragma unroll
        for (int mt = 0; mt < 4; mt++)
#pragma unroll
            for (int nt = 0; nt < 6; nt++) acc[mt][nt] = z4;
        __builtin_amdgcn_s_setprio(1);
#pragma unroll
        for (int kt = 0; kt < 6; kt++) {
            bhalf8 ag[4], sf[4];
#pragma unroll
            for (int mt = 0; mt < 4; mt++) {
                ag[mt] = *(const bhalf8*)&Ag[tok0 + (mt * 16 + l16) * 192 + kt * 32 + g * 8];
                sf[mt] = *(const bhalf8*)&s_s[(mt * 16 + l16) * 200 + kt * 32 + g * 8];
            }
#pragma unroll
            for (int nt = 0; nt < 2; nt++) {
                bhalf8 wf = *(const bhalf8*)&Wqc[((h * 12 + nt * 6 + kt) << 9) + fo];
#pragma unroll
                for (int mt = 0; mt < 4; mt++)
                    acc[mt][nt] = MFMA(ag[mt], wf, acc[mt][nt]);
            }
#pragma unroll
            for (int nt = 0; nt < 2; nt++) {
                bhalf8 wf = *(const bhalf8*)&Wkv[((h * 24 + nt * 6 + kt) << 9) + fo];
#pragma unroll
                for (int mt = 0; mt < 4; mt++)
                    acc[mt][2 + nt] = MFMA(sf[mt], wf, acc[mt][2 + nt]);
            }
#pragma unroll
            for (int nt = 0; nt < 2; nt++) {
                bhalf8 wf = *(const bhalf8*)&Wkv[((h * 24 + (nt + 2) * 6 + kt) << 9) + fo];
#pragma unroll
                for (int mt = 0; mt < 4; mt++)
                    acc[mt][4 + nt] = MFMA(sf[mt], wf, acc[mt][4 + nt]);
            }
        }
        __builtin_amdgcn_s_setprio(0);
#pragma unroll
        for (int nt = 0; nt < 6; nt++) {
            int d = (nt & 1) * 16 + l16;
#pragma unroll
            for (int mt = 0; mt < 4; mt++)
#pragma unroll
                for (int r = 0; r < 4; r++) {
                    int tok = mt * 16 + g * 4 + r;
                    short bv = f2bf(acc[mt][nt][r]);
                    if (nt < 2)      sq[tok * 40 + d] = bv;
                    else if (nt < 4) sk[tok * 40 + d] = bv;
                    else             svt[d * 72 + tok] = bv;
                }
        }
        // ---- S = Q K^T ----
        fvec4 sacc[4][4];
        {
            bhalf8 qf[4], kf[4];
#pragma unroll
            for (int mt = 0; mt < 4; mt++)
                qf[mt] = *(const bhalf8*)&sq[(mt * 16 + l16) * 40 + g * 8];
#pragma unroll
            for (int nt = 0; nt < 4; nt++)
                kf[nt] = *(const bhalf8*)&sk[(nt * 16 + l16) * 40 + g * 8];
#pragma unroll
            for (int mt = 0; mt < 4; mt++)
#pragma unroll
                for (int nt = 0; nt < 4; nt++)
                    sacc[mt][nt] = MFMA(qf[mt], kf[nt], z4);
        }
#pragma unroll
        for (int mt = 0; mt < 4; mt++) {
            float sv[4][4];
#pragma unroll
            for (int nt = 0; nt < 4; nt++)
#pragma unroll
                for (int r = 0; r < 4; r++)
                    sv[nt][r] = sacc[mt][nt][r] * SCALEF;
#pragma unroll
            for (int r = 0; r < 4; r++) {
                float m = fmaxf(fmaxf(sv[0][r], sv[1][r]), fmaxf(sv[2][r], sv[3][r]));
                m = fmaxf(m, __shfl_xor(m, 1)); m = fmaxf(m, __shfl_xor(m, 2));
                m = fmaxf(m, __shfl_xor(m, 4)); m = fmaxf(m, __shfl_xor(m, 8));
                float s = 0.f;
#pragma unroll
                for (int nt = 0; nt < 4; nt++) { sv[nt][r] = __expf(sv[nt][r] - m); s += sv[nt][r]; }
                s += __shfl_xor(s, 1); s += __shfl_xor(s, 2);
                s += __shfl_xor(s, 4); s += __shfl_xor(s, 8);
                float inv = 1.f / s;
#pragma unroll
                for (int nt = 0; nt < 4; nt++)
                    sp[(mt * 16 + g * 4 + r) * 72 + nt * 16 + l16] = f2bf(sv[nt][r] * inv);
            }
        }
        // ---- O = P V ----
        fvec4 oacc[4][2];
#pragma unroll
        for (int mt = 0; mt < 4; mt++) { oacc[mt][0] = z4; oacc[mt][1] = z4; }
#pragma unroll
        for (int ks = 0; ks < 2; ks++) {
            bhalf8 pf[4];
#pragma unroll
            for (int mt = 0; mt < 4; mt++)
                pf[mt] = *(const bhalf8*)&sp[(mt * 16 + l16) * 72 + ks * 32 + g * 8];
#pragma unroll
            for (int nt = 0; nt < 2; nt++) {
                bhalf8 vf = *(const bhalf8*)&svt[(nt * 16 + l16) * 72 + ks * 32 + g * 8];
#pragma unroll
                for (int mt = 0; mt < 4; mt++)
                    oacc[mt][nt] = MFMA(pf[mt], vf, oacc[mt][nt]);
            }
        }
#pragma unroll
        for (int nt = 0; nt < 2; nt++) {
            int d = nt * 16 + l16;
            if (d < 24) {
#pragma unroll
                for (int mt = 0; mt < 4; mt++)
#pragma unroll
                    for (int r = 0; r < 4; r++)
                        so[(mt * 16 + g * 4 + r) * 24 + d] = f2bf(oacc[mt][nt][r]);
            }
        }
    }
    __syncthreads();

    bhalf8 xst[3]; int xr[3], xc[3];
#pragma unroll
    for (int t = 0; t < 3; t++) {
        int i = tid + t * TPB2;
        int flat = i << 3; xr[t] = flat / 192; xc[t] = flat - xr[t] * 192;
        xst[t] = *(const bhalf8*)&Xg[tok0 + flat];
    }

    const int mh = w & 1, ng = w >> 1;
    fvec4 p[2][3];
#pragma unroll
    for (int m = 0; m < 2; m++)
#pragma unroll
        for (int j = 0; j < 3; j++) p[m][j] = z4;
#pragma unroll
    for (int kt = 0; kt < 6; kt++) {
        int c0 = kt * 32 + g * 8;
        int h0 = c0 / 24, d0 = c0 - h0 * 24;
        bhalf8 of[2];
#pragma unroll
        for (int m = 0; m < 2; m++)
            of[m] = *(const bhalf8*)&s_w8[h0 * PW + ((mh * 2 + m) * 16 + l16) * 24 + d0];
#pragma unroll
        for (int j = 0; j < 3; j++) {
            bhalf8 wf = *(const bhalf8*)&Wcp[(((ng * 3 + j) * 6 + kt) << 9) + fo];
#pragma unroll
            for (int m = 0; m < 2; m++)
                p[m][j] = MFMA(of[m], wf, p[m][j]);
        }
    }
#pragma unroll
    for (int t = 0; t < 3; t++)
        *(bhalf8*)&s_s[xr[t] * 200 + xc[t]] = xst[t];
    __syncthreads();

    float xv[2][3][4];
#pragma unroll
    for (int j = 0; j < 3; j++) {
        int col = ng * 48 + j * 16 + l16;
        float cp = cpb[col];
#pragma unroll
        for (int m = 0; m < 2; m++)
#pragma unroll
            for (int r = 0; r < 4; r++) {
                int row = (mh * 2 + m) * 16 + g * 4 + r;
                xv[m][j][r] = bf2f(s_s[row * 200 + col]) + p[m][j][r] + cp;
            }
    }
#pragma unroll
    for (int m = 0; m < 2; m++)
#pragma unroll
        for (int r = 0; r < 4; r++) {
            float s1 = xv[m][0][r] + xv[m][1][r] + xv[m][2][r];
            float s2 = xv[m][0][r] * xv[m][0][r] + xv[m][1][r] * xv[m][1][r] + xv[m][2][r] * xv[m][2][r];
            s1 += __shfl_xor(s1, 1); s1 += __shfl_xor(s1, 2); s1 += __shfl_xor(s1, 4); s1 += __shfl_xor(s1, 8);
            s2 += __shfl_xor(s2, 1); s2 += __shfl_xor(s2, 2); s2 += __shfl_xor(s2, 4); s2 += __shfl_xor(s2, 8);
            if (l16 == 0) {
                int row = (mh * 2 + m) * 16 + g * 4 + r;
                s_part[(ng * 64 + row) * 2]     = s1;
                s_part[(ng * 64 + row) * 2 + 1] = s2;
            }
        }
    __syncthreads();
    if (tid < 64) {
        float s1 = s_part[tid * 2] + s_part[(64 + tid) * 2] + s_part[(128 + tid) * 2] + s_part[(192 + tid) * 2];
        float s2 = s_part[tid * 2 + 1] + s_part[(64 + tid) * 2 + 1] + s_part[(128 + tid) * 2 + 1] + s_part[(192 + tid) * 2 + 1];
        float mu = s1 * (1.f / 192.f);
        float var = s2 * (1.f / 192.f) - mu * mu;
        s_mv[tid * 2] = mu;
        s_mv[tid * 2 + 1] = rsqrtf(var + 1e-6f);
    }
    __syncthreads();
#pragma unroll
    for (int j = 0; j < 3; j++) {
        int col = ng * 48 + j * 16 + l16;
        float lw = ln2w[col], lb = ln2b[col], ga = gamma[b * 192 + col], be = beta[b * 192 + col];
#pragma unroll
        for (int m = 0; m < 2; m++)
#pragma unroll
            for (int r = 0; r < 4; r++) {
                int row = (mh * 2 + m) * 16 + g * 4 + r;
                float x = xv[m][j][r];
                s_s[row * 200 + col] = f2bf(x);
                float xn = (x - s_mv[row * 2]) * s_mv[row * 2 + 1];
                s_w8[row * 200 + col] = f2bf((xn * lw + lb) * ga + be);
            }
    }
    __syncthreads();
#pragma unroll
    for (int t = 0; t < 3; t++) {
        int i = tid + t * TPB2;
        int flat = i << 3, row = flat / 192, col = flat - row * 192;
        *(bhalf8*)&Xg[tok0 + flat] = *(const bhalf8*)&s_s[row * 200 + col];
        *(bhalf8*)&Ag[tok0 + flat] = *(const bhalf8*)&s_w8[row * 200 + col];
    }
}

// ---------------- K4: fused FFN + residual (512 thr / 8 waves, high TLP) ----------------
// Wave w: GEMM1 owns hidden n-tile w of each 128-wide chunk (hacc[4]);
// GEMM2 owns rows (w&1)*32..+32 x output tiles (w>>1)*3..+3 (yacc[2][3]).
// LDS 43KB -> 3 blocks/CU -> up to 6 waves/SIMD.
__global__ __launch_bounds__(TPB2, 6) void k4_ffn(
    const short* __restrict__ Ag, const short* __restrict__ Xg,
    const short* __restrict__ W1b, const short* __restrict__ W2b,
    float* __restrict__ out)
{
    __shared__ short s_u[12800];   // A-tile 64x200; later Xg/residual/out
    __shared__ short s_h[8704];    // hidden chunk 64x136 (128 used)

    const int tid = threadIdx.x;
    const int wid = blockIdx.x;
    const int b = wid >> 8, hb = (wid >> 4) & 15, wb = wid & 15;
    const int xbase = ((b * 192) << 14) + ((hb * 8) << 7) + wb * 8;
    const int w = tid >> 6;        // wave 0..7
    const int lane = tid & 63;
    const int g = lane >> 4;
    const int l16 = lane & 15;
    const int fo = lane << 3;
    const int tok0 = wid * 12288;
    const int mh = w & 1, ng = w >> 1;
    const fvec4 z4 = {0.f, 0.f, 0.f, 0.f};

    // ---- stage A (cln2 output) into LDS, vectorized ----
#pragma unroll
    for (int t = 0; t < 3; t++) {
        int i = tid + t * TPB2;
        int flat = i << 3, row = flat / 192, col = flat - row * 192;
        *(bhalf8*)&s_u[row * 200 + col] = *(const bhalf8*)&Ag[tok0 + flat];
    }
    __syncthreads();

    fvec4 yacc[2][3];
#pragma unroll
    for (int m = 0; m < 2; m++)
#pragma unroll
        for (int j = 0; j < 3; j++) yacc[m][j] = z4;

    for (int c = 0; c < 6; c++) {
        // ---- GEMM1: wave owns hidden tile w (cols w*16..+16 of chunk) ----
        fvec4 hacc[4];
#pragma unroll
        for (int mt = 0; mt < 4; mt++) hacc[mt] = z4;
#pragma unroll
        for (int kt = 0; kt < 6; kt++) {
            bhalf8 wf = *(const bhalf8*)&W1b[(((c * 8 + w) * 6 + kt) << 9) + fo];
#pragma unroll
            for (int mt = 0; mt < 4; mt++) {
                bhalf8 af = *(const bhalf8*)&s_u[(mt * 16 + l16) * 200 + kt * 32 + g * 8];
                hacc[mt] = MFMA(af, wf, hacc[mt]);
            }
        }
        // ---- GELU (sigmoid form) -> s_h col w*16+l16, all 64 rows ----
        {
            int cc = w * 16 + l16;
#pragma unroll
            for (int mt = 0; mt < 4; mt++) {
#pragma unroll
                for (int r = 0; r < 4; r++) {
                    float x = hacc[mt][r];
                    float z = 1.5957691216f * x * (1.f + 0.044715f * x * x);
                    float gl = x / (1.f + __expf(-z));
                    s_h[(mt * 16 + g * 4 + r) * 136 + cc] = f2bf(gl);
                }
            }
        }
        __syncthreads();
        // ---- GEMM2: rows mh half, 3 output tiles ----
#pragma unroll
        for (int ks = 0; ks < 4; ks++) {
            bhalf8 hf[2];
#pragma unroll
            for (int m = 0; m < 2; m++)
                hf[m] = *(const bhalf8*)&s_h[((mh * 2 + m) * 16 + l16) * 136 + ks * 32 + g * 8];
#pragma unroll
            for (int j = 0; j < 3; j++) {
                bhalf8 wf = *(const bhalf8*)&W2b[(((ng * 3 + j) * 24 + c * 4 + ks) << 9) + fo];
#pragma unroll
                for (int m = 0; m < 2; m++)
                    yacc[m][j] = MFMA(hf[m], wf, yacc[m][j]);
            }
        }
        __syncthreads();  // s_h readers done before next chunk overwrites
    }

    // ---- stage Xg (residual) into s_u (A-tile dead) ----
#pragma unroll
    for (int t = 0; t < 3; t++) {
        int i = tid + t * TPB2;
        int flat = i << 3, row = flat / 192, col = flat - row * 192;
        *(bhalf8*)&s_u[row * 200 + col] = *(const bhalf8*)&Xg[tok0 + flat];
    }
    __syncthreads();
    // ---- residual add in place (wave owns rows mh*32..+32 x cols ng*48..+48) ----
#pragma unroll
    for (int j = 0; j < 3; j++) {
        int col = ng * 48 + j * 16 + l16;
#pragma unroll
        for (int m = 0; m < 2; m++) {
#pragma unroll
            for (int r = 0; r < 4; r++) {
                int tok = (mh * 2 + m) * 16 + g * 4 + r;
                float v = bf2f(s_u[tok * 200 + col]) + yacc[m][j][r];
                s_u[tok * 200 + col] = f2bf(v);
            }
        }
    }
    __syncthreads();
    // ---- coalesced scatter to NCHW ----
    for (int i = tid; i < 12288; i += TPB2) {
        int cc = i >> 6, l = i & 63;
        out[xbase + (cc << 14) + ((l >> 3) << 7) + (l & 7)] = bf2f(s_u[l * 200 + cc]);
    }
}

extern "C" void kernel_launch(void* const* d_in, const int* in_sizes, int n_in,
                              void* d_out, int out_size, void* d_ws, size_t ws_size,
                              hipStream_t stream) {
    const float* xrgb  = (const float*)d_in[0];
    const float* xsar  = (const float*)d_in[1];
    const float* gamma = (const float*)d_in[2];
    const float* beta  = (const float*)d_in[3];
    const float* ln1w  = (const float*)d_in[4];
    const float* ln1b  = (const float*)d_in[5];
    const float* ln2w  = (const float*)d_in[6];
    const float* ln2b  = (const float*)d_in[7];
    const float* qkvw  = (const float*)d_in[8];
    const float* qkvb  = (const float*)d_in[9];
    const float* apw   = (const float*)d_in[10];
    const float* apb   = (const float*)d_in[11];
    const float* relb  = (const float*)d_in[12];
    const float* qw    = (const float*)d_in[13];
    const float* kvw   = (const float*)d_in[14];
    const float* cpw   = (const float*)d_in[15];
    const float* cpb   = (const float*)d_in[16];
    const float* w1    = (const float*)d_in[17];
    const float* w2    = (const float*)d_in[18];

    char* base = (char*)d_ws;
    short* Wqkv = (short*)base;
    short* Wqc  = Wqkv + N_QKV;
    short* Wkv  = Wqc + N_QC;
    short* Wap  = Wkv + N_KV;
    short* Wcp  = Wap + N_AP;
    short* W1b  = Wcp + N_CP;
    short* W2b  = W1b + N_W1;
    float* qbp  = (float*)(base + (size_t)W_TOT * 2);          // 768 floats
    short* Ag   = (short*)(base + (size_t)W_TOT * 2 + 3072);   // 131072 x 192 bf16
    short* Xg   = Ag + 25165824;
    short* Sg   = Xg + 25165824;

    float* out = (float*)d_out;

    hipLaunchKernelGGL(k0_wprep, dim3(256), dim3(TPB), 0, stream,
                       qkvw, qkvb, qw, kvw, apw, cpw, w1, w2,
                       Wqkv, Wqc, Wkv, Wap, Wcp, W1b, W2b, qbp);
    hipLaunchKernelGGL(k1_prep, dim3(NWIN), dim3(TPB), 0, stream,
                       xrgb, xsar, gamma, beta, ln1w, ln1b, Ag, Xg, Sg);
    hipLaunchKernelGGL(k2_self, dim3(NWIN), dim3(TPB2), 0, stream,
                       Ag, Xg, Wqkv, qbp, Wap, apb, relb, ln1w, ln1b, gamma, beta);
    hipLaunchKernelGGL(k3_cross, dim3(NWIN), dim3(TPB2), 0, stream,
                       Ag, Xg, Sg, Wqc, Wkv, Wcp, cpb, ln2w, ln2b, gamma, beta);
    hipLaunchKernelGGL(k4_ffn, dim3(NWIN), dim3(TPB2), 0, stream,
                       Ag, Xg, W1b, W2b, out);
}

// Round 6
// 877.071 us; speedup vs baseline: 1.1158x; 1.0235x over previous
//
#include <hip/hip_runtime.h>
#include <math.h>

// FusionRestormerBlock — bf16 MFMA, fragment-ordered weights.
// v7: Sg eliminated — k3 stages x_sar directly from NCHW fp32 (same f2bf
// rounding point, identical numerics), k1 drops its SAR half (-150MB HBM
// round trip) and goes to 512 threads (24 waves/CU, k4's TLP lever).
// k2/k4 unchanged from v6.

#define TPB 256
#define TPB2 512
#define NWIN 2048
#define SCALEF 0.20412414523193154f  // 24^-0.5

typedef __attribute__((ext_vector_type(8))) short bhalf8;
typedef __attribute__((ext_vector_type(4))) float fvec4;

#define MFMA(a, b, c) __builtin_amdgcn_mfma_f32_16x16x32_bf16(a, b, c, 0, 0, 0)

__device__ __forceinline__ short f2bf(float f) {
    unsigned u = __float_as_uint(f);
    u = u + 0x7fffu + ((u >> 16) & 1u);
    return (short)(u >> 16);
}
__device__ __forceinline__ float bf2f(short s) {
    return __uint_as_float(((unsigned)(unsigned short)s) << 16);
}

// Weight region element counts (bf16 elements), all tile-packed
#define N_QKV 147456     // 8 heads x (6 nt x 6 kt) tiles
#define N_QC  49152      // 8 x (2 x 6)
#define N_KV  98304      // 8 x (4 x 6)
#define N_AP  36864      // 12 x 6
#define N_CP  36864
#define N_W1  147456     // 48 x 6
#define N_W2  147456     // 12 nt x 24 ks
#define W_TOT 663552

// per-wave LDS region (shorts): q[0:2560) k[2560:5120) vt[5120:7424)
#define PW 7424

// ---------------- K0: weight prep (fp32 -> padded bf16, fragment-tile order) ----------------
__global__ __launch_bounds__(TPB) void k0_wprep(
    const float* __restrict__ qkvw, const float* __restrict__ qkvb,
    const float* __restrict__ qw, const float* __restrict__ kvw,
    const float* __restrict__ apw, const float* __restrict__ cpw,
    const float* __restrict__ w1, const float* __restrict__ w2,
    short* __restrict__ Wqkv, short* __restrict__ Wqc, short* __restrict__ Wkv,
    short* __restrict__ Wap, short* __restrict__ Wcp, short* __restrict__ W1b,
    short* __restrict__ W2b, float* __restrict__ qbp)
{
    const int tid = blockIdx.x * TPB + threadIdx.x;
    const int stride = gridDim.x * TPB;
    for (int i = tid; i < N_QKV; i += stride) {
        int tile = i >> 9, pos = i & 511;
        int lane = pos >> 3, j = pos & 7, l16 = lane & 15, g = lane >> 4;
        int h = tile / 36, t2 = tile % 36, nt = t2 / 6, kt = t2 % 6;
        int col = nt * 16 + l16, sub = col >> 5, d = col & 31;
        int k = kt * 32 + g * 8 + j;
        float v = (d < 24) ? qkvw[(sub * 192 + h * 24 + d) * 192 + k] : 0.f;
        Wqkv[i] = f2bf(v);
    }
    for (int i = tid; i < N_QC; i += stride) {
        int tile = i >> 9, pos = i & 511;
        int lane = pos >> 3, j = pos & 7, l16 = lane & 15, g = lane >> 4;
        int h = tile / 12, t2 = tile % 12, nt = t2 / 6, kt = t2 % 6;
        int col = nt * 16 + l16;
        int k = kt * 32 + g * 8 + j;
        float v = (col < 24) ? qw[(h * 24 + col) * 192 + k] : 0.f;
        Wqc[i] = f2bf(v);
    }
    for (int i = tid; i < N_KV; i += stride) {
        int tile = i >> 9, pos = i & 511;
        int lane = pos >> 3, j = pos & 7, l16 = lane & 15, g = lane >> 4;
        int h = tile / 24, t2 = tile % 24, nt = t2 / 6, kt = t2 % 6;
        int col = nt * 16 + l16, sub = col >> 5, d = col & 31;
        int k = kt * 32 + g * 8 + j;
        float v = (d < 24) ? kvw[(sub * 192 + h * 24 + d) * 192 + k] : 0.f;
        Wkv[i] = f2bf(v);
    }
    for (int i = tid; i < N_AP; i += stride) {
        int tile = i >> 9, pos = i & 511;
        int lane = pos >> 3, j = pos & 7, l16 = lane & 15, g = lane >> 4;
        int nt = tile / 6, kt = tile % 6;
        int n = nt * 16 + l16, k = kt * 32 + g * 8 + j;
        Wap[i] = f2bf(apw[n * 192 + k]);
    }
    for (int i = tid; i < N_CP; i += stride) {
        int tile = i >> 9, pos = i & 511;
        int lane = pos >> 3, j = pos & 7, l16 = lane & 15, g = lane >> 4;
        int nt = tile / 6, kt = tile % 6;
        int n = nt * 16 + l16, k = kt * 32 + g * 8 + j;
        Wcp[i] = f2bf(cpw[n * 192 + k]);
    }
    for (int i = tid; i < N_W1; i += stride) {
        int tile = i >> 9, pos = i & 511;
        int lane = pos >> 3, j = pos & 7, l16 = lane & 15, g = lane >> 4;
        int nt = tile / 6, kt = tile % 6;
        int n = nt * 16 + l16, k = kt * 32 + g * 8 + j;
        W1b[i] = f2bf(w1[n * 192 + k]);
    }
    for (int i = tid; i < N_W2; i += stride) {
        int tile = i >> 9, pos = i & 511;
        int lane = pos >> 3, j = pos & 7, l16 = lane & 15, g = lane >> 4;
        int nt = tile / 24, ks = tile % 24;
        int n = nt * 16 + l16, k = ks * 32 + g * 8 + j;
        W2b[i] = f2bf(w2[n * 768 + k]);
    }
    for (int i = tid; i < 768; i += stride) {
        int h = i / 96, col = i % 96, sub = col >> 5, d = col & 31;
        qbp[i] = (d < 24) ? qkvb[sub * 192 + h * 24 + d] : 0.f;
    }
}

// ---------------- K1: tokenize + cln1, RGB only (512 thr, vectorized IO) ----------------
__global__ __launch_bounds__(TPB2) void k1_prep(
    const float* __restrict__ xrgb,
    const float* __restrict__ gamma, const float* __restrict__ beta,
    const float* __restrict__ ln1w, const float* __restrict__ ln1b,
    short* __restrict__ Ag, short* __restrict__ Xg)
{
    __shared__ float s_x[64 * 193];
    __shared__ float s_mu[64], s_rs[64];
    __shared__ float s_cw[768];   // ln1w | ln1b | gamma_b | beta_b
    const int tid = threadIdx.x;
    const int wid = blockIdx.x;
    const int b = wid >> 8, hb = (wid >> 4) & 15, wb = wid & 15;
    const int xbase = ((b * 192) << 14) + ((hb * 8) << 7) + wb * 8;
    const int tok0 = wid * 12288;

    if (tid < 192) {
        s_cw[tid]       = ln1w[tid];
        s_cw[192 + tid] = ln1b[tid];
        s_cw[384 + tid] = gamma[b * 192 + tid];
        s_cw[576 + tid] = beta[b * 192 + tid];
    }
    // ---- float4 loads: 192 c x 8 hrow x 2 half (6 iters) ----
    for (int i = tid; i < 3072; i += TPB2) {
        int c = i >> 4, rem = i & 15, hrow = rem >> 1, half = rem & 1;
        float4 v = *(const float4*)&xrgb[xbase + (c << 14) + (hrow << 7) + half * 4];
        int l = hrow * 8 + half * 4;
        s_x[(l + 0) * 193 + c] = v.x;
        s_x[(l + 1) * 193 + c] = v.y;
        s_x[(l + 2) * 193 + c] = v.z;
        s_x[(l + 3) * 193 + c] = v.w;
    }
    __syncthreads();
    {
        int t = tid >> 3, q8 = tid & 7;
        float sum = 0.f, sq = 0.f;
        for (int j = 0; j < 24; j++) {
            float v = s_x[t * 193 + q8 * 24 + j];
            sum += v; sq += v * v;
        }
        sum += __shfl_xor(sum, 1); sum += __shfl_xor(sum, 2); sum += __shfl_xor(sum, 4);
        sq  += __shfl_xor(sq, 1);  sq  += __shfl_xor(sq, 2);  sq  += __shfl_xor(sq, 4);
        float mu = sum * (1.f / 192.f);
        float var = sq * (1.f / 192.f) - mu * mu;
        if (q8 == 0) { s_mu[t] = mu; s_rs[t] = rsqrtf(var + 1e-6f); }
    }
    __syncthreads();
    // ---- packed bhalf8 stores (3 iters) ----
    for (int i = tid; i < 1536; i += TPB2) {
        int flat = i << 3, t = flat / 192, c0 = flat - t * 192;
        float mu = s_mu[t], rs = s_rs[t];
        bhalf8 xv, av;
#pragma unroll
        for (int j = 0; j < 8; j++) {
            float x = s_x[t * 193 + c0 + j];
            xv[j] = f2bf(x);
            float xn = (x - mu) * rs;
            av[j] = f2bf((xn * s_cw[c0 + j] + s_cw[192 + c0 + j]) * s_cw[384 + c0 + j] + s_cw[576 + c0 + j]);
        }
        *(bhalf8*)&Xg[tok0 + flat] = xv;
        *(bhalf8*)&Ag[tok0 + flat] = av;
    }
}

// ---------------- K2: fused self-attention (8 waves, 1 head/wave, LDS A-tile) ----------------
__global__ __launch_bounds__(TPB2, 2) void k2_self(
    short* __restrict__ Ag, short* __restrict__ Xg,
    const short* __restrict__ Wqkv, const float* __restrict__ qbp,
    const short* __restrict__ Wap, const float* __restrict__ apb,
    const float* __restrict__ relb,
    const float* __restrict__ ln1w, const float* __restrict__ ln1b,
    const float* __restrict__ gamma, const float* __restrict__ beta)
{
    __shared__ short s_a[12800];       // A tile 64x200 (then Xg stage, then Xg-out)
    __shared__ short s_w8[8 * PW];     // per-wave q/k/vt (sp,O overlay); then Ag-out [0:12800)
    __shared__ short s_rb[1800];
    __shared__ float s_part[512];      // [ng:4][row:64][2]
    __shared__ float s_mv[128];        // [row][mu,rs]

    const int tid = threadIdx.x;
    const int wid = blockIdx.x;
    const int b = wid >> 8;
    const int w = tid >> 6;            // wave 0..7 = head
    const int lane = tid & 63;
    const int g = lane >> 4;
    const int l16 = lane & 15;
    const int fo = lane << 3;
    const int tok0 = wid * 12288;
    short* const sq  = &s_w8[w * PW];
    short* const sk  = sq + 2560;
    short* const svt = sq + 5120;
    short* const sp  = sq;             // overlays q/k
    short* const so  = sq;             // O stash overlays sp after PV
    const fvec4 z4 = {0.f, 0.f, 0.f, 0.f};

    // ---- stage A tile (vectorized) + rel bias ----
#pragma unroll
    for (int t = 0; t < 3; t++) {
        int i = tid + t * TPB2;
        int flat = i << 3, row = flat / 192, col = flat - row * 192;
        *(bhalf8*)&s_a[row * 200 + col] = *(const bhalf8*)&Ag[tok0 + flat];
    }
    for (int i = tid; i < 1800; i += TPB2) s_rb[i] = f2bf(relb[i]);
    __syncthreads();

    {
        const int h = w;
        // ---- fused QKV GEMM (one pass, A from LDS) ----
        fvec4 acc[4][6];
#pragma unroll
        for (int mt = 0; mt < 4; mt++)
#pragma unroll
            for (int nt = 0; nt < 6; nt++) acc[mt][nt] = z4;
        __builtin_amdgcn_s_setprio(1);
#pragma unroll
        for (int kt = 0; kt < 6; kt++) {
            bhalf8 af[4];
#pragma unroll
            for (int mt = 0; mt < 4; mt++)
                af[mt] = *(const bhalf8*)&s_a[(mt * 16 + l16) * 200 + kt * 32 + g * 8];
#pragma unroll
            for (int nt = 0; nt < 6; nt++) {
                bhalf8 wf = *(const bhalf8*)&Wqkv[((h * 36 + nt * 6 + kt) << 9) + fo];
#pragma unroll
                for (int mt = 0; mt < 4; mt++)
                    acc[mt][nt] = MFMA(af[mt], wf, acc[mt][nt]);
            }
        }
        __builtin_amdgcn_s_setprio(0);
        // write Q (nt 0,1), K (nt 2,3), V^T (nt 4,5); pads d 24..31 are exact zeros
#pragma unroll
        for (int nt = 0; nt < 6; nt++) {
            float bq = qbp[h * 96 + nt * 16 + l16];
            int d = (nt & 1) * 16 + l16;
#pragma unroll
            for (int mt = 0; mt < 4; mt++)
#pragma unroll
                for (int r = 0; r < 4; r++) {
                    int tok = mt * 16 + g * 4 + r;
                    short bv = f2bf(acc[mt][nt][r] + bq);
                    if (nt < 2)      sq[tok * 40 + d] = bv;
                    else if (nt < 4) sk[tok * 40 + d] = bv;
                    else             svt[d * 72 + tok] = bv;
                }
        }
        // ---- S = Q K^T (wave-local) ----
        fvec4 sacc[4][4];
        {
            bhalf8 qf[4], kf[4];
#pragma unroll
            for (int mt = 0; mt < 4; mt++)
                qf[mt] = *(const bhalf8*)&sq[(mt * 16 + l16) * 40 + g * 8];
#pragma unroll
            for (int nt = 0; nt < 4; nt++)
                kf[nt] = *(const bhalf8*)&sk[(nt * 16 + l16) * 40 + g * 8];
#pragma unroll
            for (int mt = 0; mt < 4; mt++)
#pragma unroll
                for (int nt = 0; nt < 4; nt++)
                    sacc[mt][nt] = MFMA(qf[mt], kf[nt], z4);
        }
        // ---- softmax, P -> sp ----
#pragma unroll
        for (int mt = 0; mt < 4; mt++) {
            float sv[4][4];
#pragma unroll
            for (int nt = 0; nt < 4; nt++) {
                int n = nt * 16 + l16, ki = n >> 3, kj = n & 7;
#pragma unroll
                for (int r = 0; r < 4; r++) {
                    int qq = mt * 16 + g * 4 + r, qi = qq >> 3, qj = qq & 7;
                    int ridx = (qi - ki + 7) * 15 + (qj - kj + 7);
                    sv[nt][r] = sacc[mt][nt][r] * SCALEF + bf2f(s_rb[ridx * 8 + h]);
                }
            }
#pragma unroll
            for (int r = 0; r < 4; r++) {
                float m = fmaxf(fmaxf(sv[0][r], sv[1][r]), fmaxf(sv[2][r], sv[3][r]));
                m = fmaxf(m, __shfl_xor(m, 1)); m = fmaxf(m, __shfl_xor(m, 2));
                m = fmaxf(m, __shfl_xor(m, 4)); m = fmaxf(m, __shfl_xor(m, 8));
                float s = 0.f;
#pragma unroll
                for (int nt = 0; nt < 4; nt++) { sv[nt][r] = __expf(sv[nt][r] - m); s += sv[nt][r]; }
                s += __shfl_xor(s, 1); s += __shfl_xor(s, 2);
                s += __shfl_xor(s, 4); s += __shfl_xor(s, 8);
                float inv = 1.f / s;
#pragma unroll
                for (int nt = 0; nt < 4; nt++)
                    sp[(mt * 16 + g * 4 + r) * 72 + nt * 16 + l16] = f2bf(sv[nt][r] * inv);
            }
        }
        // ---- O = P V ----
        fvec4 oacc[4][2];
#pragma unroll
        for (int mt = 0; mt < 4; mt++) { oacc[mt][0] = z4; oacc[mt][1] = z4; }
#pragma unroll
        for (int ks = 0; ks < 2; ks++) {
            bhalf8 pf[4];
#pragma unroll
            for (int mt = 0; mt < 4; mt++)
                pf[mt] = *(const bhalf8*)&sp[(mt * 16 + l16) * 72 + ks * 32 + g * 8];
#pragma unroll
            for (int nt = 0; nt < 2; nt++) {
                bhalf8 vf = *(const bhalf8*)&svt[(nt * 16 + l16) * 72 + ks * 32 + g * 8];
#pragma unroll
                for (int mt = 0; mt < 4; mt++)
                    oacc[mt][nt] = MFMA(pf[mt], vf, oacc[mt][nt]);
            }
        }
        // ---- stash O [tok][24] in own region ----
#pragma unroll
        for (int nt = 0; nt < 2; nt++) {
            int d = nt * 16 + l16;
            if (d < 24) {
#pragma unroll
                for (int mt = 0; mt < 4; mt++)
#pragma unroll
                    for (int r = 0; r < 4; r++)
                        so[(mt * 16 + g * 4 + r) * 24 + d] = f2bf(oacc[mt][nt][r]);
            }
        }
    }
    __syncthreads();

    // ---- prefetch Xg residual into registers (hides under proj) ----
    bhalf8 xst[3]; int xr[3], xc[3];
#pragma unroll
    for (int t = 0; t < 3; t++) {
        int i = tid + t * TPB2;
        int flat = i << 3; xr[t] = flat / 192; xc[t] = flat - xr[t] * 192;
        xst[t] = *(const bhalf8*)&Xg[tok0 + flat];
    }

    // ---- proj: wave = (mh = w&1: rows mh*32..+32) x (ng = w>>1: cols ng*48..+48) ----
    const int mh = w & 1, ng = w >> 1;
    fvec4 p[2][3];
#pragma unroll
    for (int m = 0; m < 2; m++)
#pragma unroll
        for (int j = 0; j < 3; j++) p[m][j] = z4;
#pragma unroll
    for (int kt = 0; kt < 6; kt++) {
        int c0 = kt * 32 + g * 8;
        int h0 = c0 / 24, d0 = c0 - h0 * 24;
        bhalf8 of[2];
#pragma unroll
        for (int m = 0; m < 2; m++)
            of[m] = *(const bhalf8*)&s_w8[h0 * PW + ((mh * 2 + m) * 16 + l16) * 24 + d0];
#pragma unroll
        for (int j = 0; j < 3; j++) {
            bhalf8 wf = *(const bhalf8*)&Wap[(((ng * 3 + j) * 6 + kt) << 9) + fo];
#pragma unroll
            for (int m = 0; m < 2; m++)
                p[m][j] = MFMA(of[m], wf, p[m][j]);
        }
    }
    // ---- write Xg stage to s_a (A tile dead) ----
#pragma unroll
    for (int t = 0; t < 3; t++)
        *(bhalf8*)&s_a[xr[t] * 200 + xc[t]] = xst[t];
    __syncthreads();

    // ---- x1 = x_rgb + y + apb ; cross-wave LN ----
    float xv[2][3][4];
#pragma unroll
    for (int j = 0; j < 3; j++) {
        int col = ng * 48 + j * 16 + l16;
        float ap = apb[col];
#pragma unroll
        for (int m = 0; m < 2; m++)
#pragma unroll
            for (int r = 0; r < 4; r++) {
                int row = (mh * 2 + m) * 16 + g * 4 + r;
                xv[m][j][r] = bf2f(s_a[row * 200 + col]) + p[m][j][r] + ap;
            }
    }
#pragma unroll
    for (int m = 0; m < 2; m++)
#pragma unroll
        for (int r = 0; r < 4; r++) {
            float s1 = xv[m][0][r] + xv[m][1][r] + xv[m][2][r];
            float s2 = xv[m][0][r] * xv[m][0][r] + xv[m][1][r] * xv[m][1][r] + xv[m][2][r] * xv[m][2][r];
            s1 += __shfl_xor(s1, 1); s1 += __shfl_xor(s1, 2); s1 += __shfl_xor(s1, 4); s1 += __shfl_xor(s1, 8);
            s2 += __shfl_xor(s2, 1); s2 += __shfl_xor(s2, 2); s2 += __shfl_xor(s2, 4); s2 += __shfl_xor(s2, 8);
            if (l16 == 0) {
                int row = (mh * 2 + m) * 16 + g * 4 + r;
                s_part[(ng * 64 + row) * 2]     = s1;
                s_part[(ng * 64 + row) * 2 + 1] = s2;
            }
        }
    __syncthreads();
    if (tid < 64) {
        float s1 = s_part[tid * 2] + s_part[(64 + tid) * 2] + s_part[(128 + tid) * 2] + s_part[(192 + tid) * 2];
        float s2 = s_part[tid * 2 + 1] + s_part[(64 + tid) * 2 + 1] + s_part[(128 + tid) * 2 + 1] + s_part[(192 + tid) * 2 + 1];
        float mu = s1 * (1.f / 192.f);
        float var = s2 * (1.f / 192.f) - mu * mu;
        s_mv[tid * 2] = mu;
        s_mv[tid * 2 + 1] = rsqrtf(var + 1e-6f);
    }
    __syncthreads();
    // ---- stage Xg-out into s_a, Ag-out into s_w8[0:12800) ----
#pragma unroll
    for (int j = 0; j < 3; j++) {
        int col = ng * 48 + j * 16 + l16;
        float lw = ln1w[col], lb = ln1b[col], ga = gamma[b * 192 + col], be = beta[b * 192 + col];
#pragma unroll
        for (int m = 0; m < 2; m++)
#pragma unroll
            for (int r = 0; r < 4; r++) {
                int row = (mh * 2 + m) * 16 + g * 4 + r;
                float x = xv[m][j][r];
                s_a[row * 200 + col] = f2bf(x);
                float xn = (x - s_mv[row * 2]) * s_mv[row * 2 + 1];
                s_w8[row * 200 + col] = f2bf((xn * lw + lb) * ga + be);
            }
    }
    __syncthreads();
#pragma unroll
    for (int t = 0; t < 3; t++) {
        int i = tid + t * TPB2;
        int flat = i << 3, row = flat / 192, col = flat - row * 192;
        *(bhalf8*)&Xg[tok0 + flat] = *(const bhalf8*)&s_a[row * 200 + col];
        *(bhalf8*)&Ag[tok0 + flat] = *(const bhalf8*)&s_w8[row * 200 + col];
    }
}

// ---------------- K3: fused cross-attention (8 waves, 1 head/wave, SAR staged from fp32) ----------------
__global__ __launch_bounds__(TPB2, 2) void k3_cross(
    short* __restrict__ Ag, short* __restrict__ Xg, const float* __restrict__ xsar,
    const short* __restrict__ Wqc, const short* __restrict__ Wkv,
    const short* __restrict__ Wcp, const float* __restrict__ cpb,
    const float* __restrict__ ln2w, const float* __restrict__ ln2b,
    const float* __restrict__ gamma, const float* __restrict__ beta)
{
    __shared__ short s_s[12800];       // SAR tile 64x200 (then Xg stage, then Xg-out)
    __shared__ short s_w8[8 * PW];
    __shared__ float s_part[512];
    __shared__ float s_mv[128];

    const int tid = threadIdx.x;
    const int wid = blockIdx.x;
    const int b = wid >> 8, hb = (wid >> 4) & 15, wb = wid & 15;
    const int xbase = ((b * 192) << 14) + ((hb * 8) << 7) + wb * 8;
    const int w = tid >> 6;
    const int lane = tid & 63;
    const int g = lane >> 4;
    const int l16 = lane & 15;
    const int fo = lane << 3;
    const int tok0 = wid * 12288;
    short* const sq  = &s_w8[w * PW];
    short* const sk  = sq + 2560;
    short* const svt = sq + 5120;
    short* const sp  = sq;
    short* const so  = sq;
    const fvec4 z4 = {0.f, 0.f, 0.f, 0.f};

    // ---- stage SAR tile directly from NCHW fp32 (transpose + f2bf) ----
    for (int i = tid; i < 3072; i += TPB2) {
        int c = i >> 4, rem = i & 15, hrow = rem >> 1, half = rem & 1;
        float4 v = *(const float4*)&xsar[xbase + (c << 14) + (hrow << 7) + half * 4];
        int l = hrow * 8 + half * 4;
        s_s[(l + 0) * 200 + c] = f2bf(v.x);
        s_s[(l + 1) * 200 + c] = f2bf(v.y);
        s_s[(l + 2) * 200 + c] = f2bf(v.z);
        s_s[(l + 3) * 200 + c] = f2bf(v.w);
    }
    __syncthreads();

    {
        const int h = w;
        // ---- fused pass: Q (Ag global x Wqc), K,V (S-LDS x Wkv) ----
        fvec4 acc[4][6];   // 0,1=Q  2,3=K  4,5=V
#pragma unroll
        for (int mt = 0; mt < 4; mt++)
#pragma unroll
            for (int nt = 0; nt < 6; nt++) acc[mt][nt] = z4;
        __builtin_amdgcn_s_setprio(1);
#pragma unroll
        for (int kt = 0; kt < 6; kt++) {
            bhalf8 ag[4], sf[4];
#pragma unroll
            for (int mt = 0; mt < 4; mt++) {
                ag[mt] = *(const bhalf8*)&Ag[tok0 + (mt * 16 + l16) * 192 + kt * 32 + g * 8];
                sf[mt] = *(const bhalf8*)&s_s[(mt * 16 + l16) * 200 + kt * 32 + g * 8];
            }
#pragma unroll
            for (int nt = 0; nt < 2; nt++) {
                bhalf8 wf = *(const bhalf8*)&Wqc[((h * 12 + nt * 6 + kt) << 9) + fo];
#pragma unroll
                for (int mt = 0; mt < 4; mt++)
                    acc[mt][nt] = MFMA(ag[mt], wf, acc[mt][nt]);
            }
#pragma unroll
            for (int nt = 0; nt < 2; nt++) {
                bhalf8 wf = *(const bhalf8*)&Wkv[((h * 24 + nt * 6 + kt) << 9) + fo];
#pragma unroll
                for (int mt = 0; mt < 4; mt++)
                    acc[mt][2 + nt] = MFMA(sf[mt], wf, acc[mt][2 + nt]);
            }
#pragma unroll
            for (int nt = 0; nt < 2; nt++) {
                bhalf8 wf = *(const bhalf8*)&Wkv[((h * 24 + (nt + 2) * 6 + kt) << 9) + fo];
#pragma unroll
                for (int mt = 0; mt < 4; mt++)
                    acc[mt][4 + nt] = MFMA(sf[mt], wf, acc[mt][4 + nt]);
            }
        }
        __builtin_amdgcn_s_setprio(0);
#pragma unroll
        for (int nt = 0; nt < 6; nt++) {
            int d = (nt & 1) * 16 + l16;
#pragma unroll
            for (int mt = 0; mt < 4; mt++)
#pragma unroll
                for (int r = 0; r < 4; r++) {
                    int tok = mt * 16 + g * 4 + r;
                    short bv = f2bf(acc[mt][nt][r]);
                    if (nt < 2)      sq[tok * 40 + d] = bv;
                    else if (nt < 4) sk[tok * 40 + d] = bv;
                    else             svt[d * 72 + tok] = bv;
                }
        }
        // ---- S = Q K^T ----
        fvec4 sacc[4][4];
        {
            bhalf8 qf[4], kf[4];
#pragma unroll
            for (int mt = 0; mt < 4; mt++)
                qf[mt] = *(const bhalf8*)&sq[(mt * 16 + l16) * 40 + g * 8];
#pragma unroll
            for (int nt = 0; nt < 4; nt++)
                kf[nt] = *(const bhalf8*)&sk[(nt * 16 + l16) * 40 + g * 8];
#pragma unroll
            for (int mt = 0; mt < 4; mt++)
#pragma unroll
                for (int nt = 0; nt < 4; nt++)
                    sacc[mt][nt] = MFMA(qf[mt], kf[nt], z4);
        }
#pragma unroll
        for (int mt = 0; mt < 4; mt++) {
            float sv[4][4];
#pragma unroll
            for (int nt = 0; nt < 4; nt++)
#pragma unroll
                for (int r = 0; r < 4; r++)
                    sv[nt][r] = sacc[mt][nt][r] * SCALEF;
#pragma unroll
            for (int r = 0; r < 4; r++) {
                float m = fmaxf(fmaxf(sv[0][r], sv[1][r]), fmaxf(sv[2][r], sv[3][r]));
                m = fmaxf(m, __shfl_xor(m, 1)); m = fmaxf(m, __shfl_xor(m, 2));
                m = fmaxf(m, __shfl_xor(m, 4)); m = fmaxf(m, __shfl_xor(m, 8));
                float s = 0.f;
#pragma unroll
                for (int nt = 0; nt < 4; nt++) { sv[nt][r] = __expf(sv[nt][r] - m); s += sv[nt][r]; }
                s += __shfl_xor(s, 1); s += __shfl_xor(s, 2);
                s += __shfl_xor(s, 4); s += __shfl_xor(s, 8);
                float inv = 1.f / s;
#pragma unroll
                for (int nt = 0; nt < 4; nt++)
                    sp[(mt * 16 + g * 4 + r) * 72 + nt * 16 + l16] = f2bf(sv[nt][r] * inv);
            }
        }
        // ---- O = P V ----
        fvec4 oacc[4][2];
#pragma unroll
        for (int mt = 0; mt < 4; mt++) { oacc[mt][0] = z4; oacc[mt][1] = z4; }
#pragma unroll
        for (int ks = 0; ks < 2; ks++) {
            bhalf8 pf[4];
#pragma unroll
            for (int mt = 0; mt < 4; mt++)
                pf[mt] = *(const bhalf8*)&sp[(mt * 16 + l16) * 72 + ks * 32 + g * 8];
#pragma unroll
            for (int nt = 0; nt < 2; nt++) {
                bhalf8 vf = *(const bhalf8*)&svt[(nt * 16 + l16) * 72 + ks * 32 + g * 8];
#pragma unroll
                for (int mt = 0; mt < 4; mt++)
                    oacc[mt][nt] = MFMA(pf[mt], vf, oacc[mt][nt]);
            }
        }
#pragma unroll
        for (int nt = 0; nt < 2; nt++) {
            int d = nt * 16 + l16;
            if (d < 24) {
#pragma unroll
                for (int mt = 0; mt < 4; mt++)
#pragma unroll
                    for (int r = 0; r < 4; r++)
                        so[(mt * 16 + g * 4 + r) * 24 + d] = f2bf(oacc[mt][nt][r]);
            }
        }
    }
    __syncthreads();

    bhalf8 xst[3]; int xr[3], xc[3];
#pragma unroll
    for (int t = 0; t < 3; t++) {
        int i = tid + t * TPB2;
        int flat = i << 3; xr[t] = flat / 192; xc[t] = flat - xr[t] * 192;
        xst[t] = *(const bhalf8*)&Xg[tok0 + flat];
    }

    const int mh = w & 1, ng = w >> 1;
    fvec4 p[2][3];
#pragma unroll
    for (int m = 0; m < 2; m++)
#pragma unroll
        for (int j = 0; j < 3; j++) p[m][j] = z4;
#pragma unroll
    for (int kt = 0; kt < 6; kt++) {
        int c0 = kt * 32 + g * 8;
        int h0 = c0 / 24, d0 = c0 - h0 * 24;
        bhalf8 of[2];
#pragma unroll
        for (int m = 0; m < 2; m++)
            of[m] = *(const bhalf8*)&s_w8[h0 * PW + ((mh * 2 + m) * 16 + l16) * 24 + d0];
#pragma unroll
        for (int j = 0; j < 3; j++) {
            bhalf8 wf = *(const bhalf8*)&Wcp[(((ng * 3 + j) * 6 + kt) << 9) + fo];
#pragma unroll
            for (int m = 0; m < 2; m++)
                p[m][j] = MFMA(of[m], wf, p[m][j]);
        }
    }
#pragma unroll
    for (int t = 0; t < 3; t++)
        *(bhalf8*)&s_s[xr[t] * 200 + xc[t]] = xst[t];
    __syncthreads();

    float xv[2][3][4];
#pragma unroll
    for (int j = 0; j < 3; j++) {
        int col = ng * 48 + j * 16 + l16;
        float cp = cpb[col];
#pragma unroll
        for (int m = 0; m < 2; m++)
#pragma unroll
            for (int r = 0; r < 4; r++) {
                int row = (mh * 2 + m) * 16 + g * 4 + r;
                xv[m][j][r] = bf2f(s_s[row * 200 + col]) + p[m][j][r] + cp;
            }
    }
#pragma unroll
    for (int m = 0; m < 2; m++)
#pragma unroll
        for (int r = 0; r < 4; r++) {
            float s1 = xv[m][0][r] + xv[m][1][r] + xv[m][2][r];
            float s2 = xv[m][0][r] * xv[m][0][r] + xv[m][1][r] * xv[m][1][r] + xv[m][2][r] * xv[m][2][r];
            s1 += __shfl_xor(s1, 1); s1 += __shfl_xor(s1, 2); s1 += __shfl_xor(s1, 4); s1 += __shfl_xor(s1, 8);
            s2 += __shfl_xor(s2, 1); s2 += __shfl_xor(s2, 2); s2 += __shfl_xor(s2, 4); s2 += __shfl_xor(s2, 8);
            if (l16 == 0) {
                int row = (mh * 2 + m) * 16 + g * 4 + r;
                s_part[(ng * 64 + row) * 2]     = s1;
                s_part[(ng * 64 + row) * 2 + 1] = s2;
            }
        }
    __syncthreads();
    if (tid < 64) {
        float s1 = s_part[tid * 2] + s_part[(64 + tid) * 2] + s_part[(128 + tid) * 2] + s_part[(192 + tid) * 2];
        float s2 = s_part[tid * 2 + 1] + s_part[(64 + tid) * 2 + 1] + s_part[(128 + tid) * 2 + 1] + s_part[(192 + tid) * 2 + 1];
        float mu = s1 * (1.f / 192.f);
        float var = s2 * (1.f / 192.f) - mu * mu;
        s_mv[tid * 2] = mu;
        s_mv[tid * 2 + 1] = rsqrtf(var + 1e-6f);
    }
    __syncthreads();
#pragma unroll
    for (int j = 0; j < 3; j++) {
        int col = ng * 48 + j * 16 + l16;
        float lw = ln2w[col], lb = ln2b[col], ga = gamma[b * 192 + col], be = beta[b * 192 + col];
#pragma unroll
        for (int m = 0; m < 2; m++)
#pragma unroll
            for (int r = 0; r < 4; r++) {
                int row = (mh * 2 + m) * 16 + g * 4 + r;
                float x = xv[m][j][r];
                s_s[row * 200 + col] = f2bf(x);
                float xn = (x - s_mv[row * 2]) * s_mv[row * 2 + 1];
                s_w8[row * 200 + col] = f2bf((xn * lw + lb) * ga + be);
            }
    }
    __syncthreads();
#pragma unroll
    for (int t = 0; t < 3; t++) {
        int i = tid + t * TPB2;
        int flat = i << 3, row = flat / 192, col = flat - row * 192;
        *(bhalf8*)&Xg[tok0 + flat] = *(const bhalf8*)&s_s[row * 200 + col];
        *(bhalf8*)&Ag[tok0 + flat] = *(const bhalf8*)&s_w8[row * 200 + col];
    }
}

// ---------------- K4: fused FFN + residual (512 thr / 8 waves, high TLP) ----------------
__global__ __launch_bounds__(TPB2, 6) void k4_ffn(
    const short* __restrict__ Ag, const short* __restrict__ Xg,
    const short* __restrict__ W1b, const short* __restrict__ W2b,
    float* __restrict__ out)
{
    __shared__ short s_u[12800];   // A-tile 64x200; later Xg/residual/out
    __shared__ short s_h[8704];    // hidden chunk 64x136 (128 used)

    const int tid = threadIdx.x;
    const int wid = blockIdx.x;
    const int b = wid >> 8, hb = (wid >> 4) & 15, wb = wid & 15;
    const int xbase = ((b * 192) << 14) + ((hb * 8) << 7) + wb * 8;
    const int w = tid >> 6;        // wave 0..7
    const int lane = tid & 63;
    const int g = lane >> 4;
    const int l16 = lane & 15;
    const int fo = lane << 3;
    const int tok0 = wid * 12288;
    const int mh = w & 1, ng = w >> 1;
    const fvec4 z4 = {0.f, 0.f, 0.f, 0.f};

    // ---- stage A (cln2 output) into LDS, vectorized ----
#pragma unroll
    for (int t = 0; t < 3; t++) {
        int i = tid + t * TPB2;
        int flat = i << 3, row = flat / 192, col = flat - row * 192;
        *(bhalf8*)&s_u[row * 200 + col] = *(const bhalf8*)&Ag[tok0 + flat];
    }
    __syncthreads();

    fvec4 yacc[2][3];
#pragma unroll
    for (int m = 0; m < 2; m++)
#pragma unroll
        for (int j = 0; j < 3; j++) yacc[m][j] = z4;

    for (int c = 0; c < 6; c++) {
        // ---- GEMM1: wave owns hidden tile w (cols w*16..+16 of chunk) ----
        fvec4 hacc[4];
#pragma unroll
        for (int mt = 0; mt < 4; mt++) hacc[mt] = z4;
#pragma unroll
        for (int kt = 0; kt < 6; kt++) {
            bhalf8 wf = *(const bhalf8*)&W1b[(((c * 8 + w) * 6 + kt) << 9) + fo];
#pragma unroll
            for (int mt = 0; mt < 4; mt++) {
                bhalf8 af = *(const bhalf8*)&s_u[(mt * 16 + l16) * 200 + kt * 32 + g * 8];
                hacc[mt] = MFMA(af, wf, hacc[mt]);
            }
        }
        // ---- GELU (sigmoid form) -> s_h col w*16+l16, all 64 rows ----
        {
            int cc = w * 16 + l16;
#pragma unroll
            for (int mt = 0; mt < 4; mt++) {
#pragma unroll
                for (int r = 0; r < 4; r++) {
                    float x = hacc[mt][r];
                    float z = 1.5957691216f * x * (1.f + 0.044715f * x * x);
                    float gl = x / (1.f + __expf(-z));
                    s_h[(mt * 16 + g * 4 + r) * 136 + cc] = f2bf(gl);
                }
            }
        }
        __syncthreads();
        // ---- GEMM2: rows mh half, 3 output tiles ----
#pragma unroll
        for (int ks = 0; ks < 4; ks++) {
            bhalf8 hf[2];
#pragma unroll
            for (int m = 0; m < 2; m++)
                hf[m] = *(const bhalf8*)&s_h[((mh * 2 + m) * 16 + l16) * 136 + ks * 32 + g * 8];
#pragma unroll
            for (int j = 0; j < 3; j++) {
                bhalf8 wf = *(const bhalf8*)&W2b[(((ng * 3 + j) * 24 + c * 4 + ks) << 9) + fo];
#pragma unroll
                for (int m = 0; m < 2; m++)
                    yacc[m][j] = MFMA(hf[m], wf, yacc[m][j]);
            }
        }
        __syncthreads();  // s_h readers done before next chunk overwrites
    }

    // ---- stage Xg (residual) into s_u (A-tile dead) ----
#pragma unroll
    for (int t = 0; t < 3; t++) {
        int i = tid + t * TPB2;
        int flat = i << 3, row = flat / 192, col = flat - row * 192;
        *(bhalf8*)&s_u[row * 200 + col] = *(const bhalf8*)&Xg[tok0 + flat];
    }
    __syncthreads();
    // ---- residual add in place (wave owns rows mh*32..+32 x cols ng*48..+48) ----
#pragma unroll
    for (int j = 0; j < 3; j++) {
        int col = ng * 48 + j * 16 + l16;
#pragma unroll
        for (int m = 0; m < 2; m++) {
#pragma unroll
            for (int r = 0; r < 4; r++) {
                int tok = (mh * 2 + m) * 16 + g * 4 + r;
                float v = bf2f(s_u[tok * 200 + col]) + yacc[m][j][r];
                s_u[tok * 200 + col] = f2bf(v);
            }
        }
    }
    __syncthreads();
    // ---- coalesced scatter to NCHW ----
    for (int i = tid; i < 12288; i += TPB2) {
        int cc = i >> 6, l = i & 63;
        out[xbase + (cc << 14) + ((l >> 3) << 7) + (l & 7)] = bf2f(s_u[l * 200 + cc]);
    }
}

extern "C" void kernel_launch(void* const* d_in, const int* in_sizes, int n_in,
                              void* d_out, int out_size, void* d_ws, size_t ws_size,
                              hipStream_t stream) {
    const float* xrgb  = (const float*)d_in[0];
    const float* xsar  = (const float*)d_in[1];
    const float* gamma = (const float*)d_in[2];
    const float* beta  = (const float*)d_in[3];
    const float* ln1w  = (const float*)d_in[4];
    const float* ln1b  = (const float*)d_in[5];
    const float* ln2w  = (const float*)d_in[6];
    const float* ln2b  = (const float*)d_in[7];
    const float* qkvw  = (const float*)d_in[8];
    const float* qkvb  = (const float*)d_in[9];
    const float* apw   = (const float*)d_in[10];
    const float* apb   = (const float*)d_in[11];
    const float* relb  = (const float*)d_in[12];
    const float* qw    = (const float*)d_in[13];
    const float* kvw   = (const float*)d_in[14];
    const float* cpw   = (const float*)d_in[15];
    const float* cpb   = (const float*)d_in[16];
    const float* w1    = (const float*)d_in[17];
    const float* w2    = (const float*)d_in[18];

    char* base = (char*)d_ws;
    short* Wqkv = (short*)base;
    short* Wqc  = Wqkv + N_QKV;
    short* Wkv  = Wqc + N_QC;
    short* Wap  = Wkv + N_KV;
    short* Wcp  = Wap + N_AP;
    short* W1b  = Wcp + N_CP;
    short* W2b  = W1b + N_W1;
    float* qbp  = (float*)(base + (size_t)W_TOT * 2);          // 768 floats
    short* Ag   = (short*)(base + (size_t)W_TOT * 2 + 3072);   // 131072 x 192 bf16
    short* Xg   = Ag + 25165824;

    float* out = (float*)d_out;

    hipLaunchKernelGGL(k0_wprep, dim3(256), dim3(TPB), 0, stream,
                       qkvw, qkvb, qw, kvw, apw, cpw, w1, w2,
                       Wqkv, Wqc, Wkv, Wap, Wcp, W1b, W2b, qbp);
    hipLaunchKernelGGL(k1_prep, dim3(NWIN), dim3(TPB2), 0, stream,
                       xrgb, gamma, beta, ln1w, ln1b, Ag, Xg);
    hipLaunchKernelGGL(k2_self, dim3(NWIN), dim3(TPB2), 0, stream,
                       Ag, Xg, Wqkv, qbp, Wap, apb, relb, ln1w, ln1b, gamma, beta);
    hipLaunchKernelGGL(k3_cross, dim3(NWIN), dim3(TPB2), 0, stream,
                       Ag, Xg, xsar, Wqc, Wkv, Wcp, cpb, ln2w, ln2b, gamma, beta);
    hipLaunchKernelGGL(k4_ffn, dim3(NWIN), dim3(TPB2), 0, stream,
                       Ag, Xg, W1b, W2b, out);
}